// Round 15
// baseline (197.485 us; speedup 1.0000x reference)
//
#include <hip/hip_runtime.h>

using u16 = unsigned short;
using u32 = unsigned int;
typedef __attribute__((ext_vector_type(8))) short bf16x8;
typedef __attribute__((ext_vector_type(4))) short bf16x4;
typedef __attribute__((ext_vector_type(4))) float f32x4;
typedef __attribute__((ext_vector_type(16))) float f32x16;
typedef __attribute__((ext_vector_type(4))) u32 u32x4;

__device__ __forceinline__ u16 f2bf(float f) {
  u32 u = __builtin_bit_cast(u32, f);
  u += 0x7FFFu + ((u >> 16) & 1u);
  return (u16)(u >> 16);
}

__device__ __forceinline__ void load_lds16(const void* g, void* l) {
  typedef const __attribute__((address_space(1))) u32 GA;
  typedef __attribute__((address_space(3))) u32 LA;
  __builtin_amdgcn_global_load_lds((GA*)g, (LA*)l, 16, 0, 0);
}

__device__ __forceinline__ bf16x4 tr16(const u16* p) {
  typedef __attribute__((address_space(3))) const u16 LT;
  bf16x4 d;
  asm volatile("ds_read_b64_tr_b16 %0, %1" : "=v"(d) : "v"((LT*)p));
  return d;
}

__device__ __forceinline__ float exp2_fast(float x) {
  float r;
  asm("v_exp_f32 %0, %1" : "=v"(r) : "v"(x));
  return r;
}

__device__ __forceinline__ u32 cvt_pk_bf16(float lo, float hi) {
  u32 r;
  asm("v_cvt_pk_bf16_f32 %0, %1, %2" : "=v"(r) : "v"(lo), "v"(hi));
  return r;
}

__device__ __forceinline__ void permlane32_swap(u32& a, u32& b) {
  asm volatile("v_permlane32_swap_b32 %0, %1" : "+v"(a), "+v"(b));
}

// ---------------- fused f32 -> bf16 conversion (hs + 4 weights, one launch) ----
__global__ void cvt_all(const float* __restrict__ hs, const float* __restrict__ Wq,
                        const float* __restrict__ Wk, const float* __restrict__ Wv,
                        const float* __restrict__ Wo, u16* __restrict__ hs16,
                        u16* __restrict__ w16, int hs4, int w4seg, float qscale) {
  int i = blockIdx.x * blockDim.x + threadIdx.x;
  const float* src;
  u16* dst;
  float sc = 1.0f;
  int off;
  if (i < hs4) {
    src = hs; dst = hs16; off = i;
  } else {
    int j = i - hs4;
    int seg = j / w4seg;
    off = j - seg * w4seg;
    dst = w16 + (size_t)seg * (size_t)w4seg * 4;
    src = seg == 0 ? Wq : seg == 1 ? Wk : seg == 2 ? Wv : Wo;
    if (seg == 0) sc = qscale;
  }
  float4 v = reinterpret_cast<const float4*>(src)[off];
  ushort4 o;
  o.x = f2bf(v.x * sc);
  o.y = f2bf(v.y * sc);
  o.z = f2bf(v.z * sc);
  o.w = f2bf(v.w * sc);
  reinterpret_cast<ushort4*>(dst)[off] = o;
}

// ---------------- bf16 GEMM (legacy 128x128, for Wo) ----------------
template <typename OutT>
__global__ __launch_bounds__(256, 2) void gemm_bt(
    const u16* __restrict__ A, const u16* __restrict__ Bw,
    OutT* __restrict__ C, int M, int N, int K) {
  __shared__ u16 At[128 * 32];
  __shared__ u16 Bt[128 * 32];
  const int tid = threadIdx.x;
  const int wid = tid >> 6, lane = tid & 63;
  const int wr = wid >> 1, wc = wid & 1;
  const int laneR = lane & 15, laneG = lane >> 4;
  const int laneK = laneG * 8;

  const int nbm = M >> 7;
  const int cpx = gridDim.x >> 3;
  const int id = blockIdx.x;
  const int swz = (id & 7) * cpx + (id >> 3);
  const int bm = swz % nbm, bn = swz / nbm;

  f32x4 acc[4][4];
#pragma unroll
  for (int i = 0; i < 4; ++i)
#pragma unroll
    for (int j = 0; j < 4; ++j) acc[i][j] = f32x4{0.f, 0.f, 0.f, 0.f};

  const int e0 = tid * 8;
  const int r0 = e0 >> 5, c0 = e0 & 31;
  const u16* Ab = A + (size_t)(bm * 128) * K;
  const u16* Bb = Bw + (size_t)(bn * 128) * K;

  for (int k0 = 0; k0 < K; k0 += 32) {
#pragma unroll
    for (int i = 0; i < 2; ++i) {
      load_lds16(Ab + (size_t)(i * 64 + r0) * K + k0 + c0, &At[(i * 256 + wid * 64) * 8]);
      load_lds16(Bb + (size_t)(i * 64 + r0) * K + k0 + c0, &Bt[(i * 256 + wid * 64) * 8]);
    }
    __syncthreads();
    bf16x8 af[4], bfr[4];
#pragma unroll
    for (int i = 0; i < 4; ++i)
      af[i] = *(const bf16x8*)&At[(wr * 64 + i * 16 + laneR) * 32 + laneK];
#pragma unroll
    for (int j = 0; j < 4; ++j)
      bfr[j] = *(const bf16x8*)&Bt[(wc * 64 + j * 16 + laneR) * 32 + laneK];
#pragma unroll
    for (int i = 0; i < 4; ++i)
#pragma unroll
      for (int j = 0; j < 4; ++j)
        acc[i][j] = __builtin_amdgcn_mfma_f32_16x16x32_bf16(af[i], bfr[j], acc[i][j], 0, 0, 0);
    __syncthreads();
  }

  const int crow = bm * 128 + wr * 64;
  const int ccol = bn * 128 + wc * 64;
#pragma unroll
  for (int i = 0; i < 4; ++i)
#pragma unroll
    for (int j = 0; j < 4; ++j)
#pragma unroll
      for (int r = 0; r < 4; ++r) {
        int row = crow + i * 16 + laneG * 4 + r;
        int col = ccol + j * 16 + laneR;
        float v = acc[i][j][r];
        if constexpr (sizeof(OutT) == 2)
          C[(size_t)row * N + col] = f2bf(v);
        else
          C[(size_t)row * N + col] = v;
      }
}

// ---------------- 256x256 8-phase GEMM, 32x32x16 MFMA ----------------
// Same staging/barrier/vmcnt schedule as R11; fragment reads + MFMA cluster
// switched to 32x32x16 (A/B layout: lane(lq,hi) holds X[lq][8*hi+j] per K=16
// slice; D: row=(r&3)+8*(r>>2)+4*hi, col=lq — verified in flash since R6).
template <int MH, int NF>
__device__ __forceinline__ void m32q(f32x16 (&acc)[4][2], bf16x8 (&af)[2][4],
                                     bf16x8 (&bf)[4]) {
  __builtin_amdgcn_s_setprio(1);
#pragma unroll
  for (int ml = 0; ml < 2; ++ml)
#pragma unroll
    for (int ks = 0; ks < 4; ++ks)
      acc[MH * 2 + ml][NF] = __builtin_amdgcn_mfma_f32_32x32x16_bf16(
          af[ml][ks], bf[ks], acc[MH * 2 + ml][NF], 0, 0, 0);
  __builtin_amdgcn_s_setprio(0);
}

#define GBAR() __builtin_amdgcn_s_barrier()
#define PWAIT()                                            \
  do {                                                     \
    GBAR();                                                \
    asm volatile("s_waitcnt lgkmcnt(0)" ::: "memory");     \
  } while (0)
#define PWAITV()                                                    \
  do {                                                              \
    GBAR();                                                         \
    asm volatile("s_waitcnt vmcnt(2) lgkmcnt(0)" ::: "memory");     \
  } while (0)

template <typename OutT>
__global__ __launch_bounds__(512, 2) void gemm256(
    const u16* __restrict__ A, const u16* __restrict__ Bw,
    OutT* __restrict__ C, int M, int N, int K) {
  __shared__ __align__(16) char ldsb[131072];
  const int tid = threadIdx.x;
  const int wid = tid >> 6, lane = tid & 63;
  const int wr = wid >> 2, wc = wid & 3;
  const int lq = lane & 31, hi = lane >> 5;

  const int nbm = M >> 8;
  const int cpx = gridDim.x >> 3;
  const int id = blockIdx.x;
  const int swzid = (id & 7) * cpx + (id >> 3);
  const int bm = swzid % nbm, bn = swzid / nbm;

  const u16* Ab = A + (size_t)(bm * 256) * K;
  const u16* Bb = Bw + (size_t)(bn * 256) * K;

  const int s_r = tid >> 3;
  const int s_k = ((tid & 7) ^ (s_r & 7)) * 8;

  auto stage_half = [&](const u16* Xb, int regio, int buf, int hh, int kt) {
    char* d = ldsb + regio + buf * 32768 + hh * 16384 + wid * 1024;
#pragma unroll
    for (int j = 0; j < 2; ++j)
      load_lds16(Xb + (size_t)(hh * 128 + j * 64 + s_r) * K + kt * 64 + s_k,
                 d + j * 8192);
  };
  // A: wave wr owns half wr (rows wr*128..+127); frag mf rows = mf*32+lq
  auto rdA32 = [&](int buf, int mf, int ks) -> bf16x8 {
    return *(const bf16x8*)(ldsb + buf * 32768 + wr * 16384 +
                            (mf * 32 + lq) * 128 +
                            ((ks * 32 + hi * 16) ^ ((lq & 7) << 4)));
  };
  // B: wave wc owns cols wc*64..+63; frag nf rows = (wc&1)*64 + nf*32 + lq
  auto rdB32 = [&](int buf, int nf, int ks) -> bf16x8 {
    return *(const bf16x8*)(ldsb + 65536 + buf * 32768 + (wc >> 1) * 16384 +
                            ((wc & 1) * 64 + nf * 32 + lq) * 128 +
                            ((ks * 32 + hi * 16) ^ ((lq & 7) << 4)));
  };

  f32x16 acc[4][2];
#pragma unroll
  for (int i = 0; i < 4; ++i)
#pragma unroll
    for (int j = 0; j < 2; ++j)
#pragma unroll
      for (int r = 0; r < 16; ++r) acc[i][j][r] = 0.f;

  bf16x8 af[2][4], bf[4];
  auto readA32 = [&](int buf, int MH) {
#pragma unroll
    for (int ml = 0; ml < 2; ++ml)
#pragma unroll
      for (int ks = 0; ks < 4; ++ks) af[ml][ks] = rdA32(buf, MH * 2 + ml, ks);
  };
  auto readB32 = [&](int buf, int NF) {
#pragma unroll
    for (int ks = 0; ks < 4; ++ks) bf[ks] = rdB32(buf, NF, ks);
  };

  const int NT = K >> 6, NI = K >> 7;

  stage_half(Ab, 0, 0, 0, 0);
  stage_half(Ab, 0, 0, 1, 0);
  stage_half(Bb, 65536, 0, 0, 0);
  stage_half(Bb, 65536, 0, 1, 0);
  stage_half(Ab, 0, 1, 0, 1);
  asm volatile("s_waitcnt vmcnt(2)" ::: "memory");
  GBAR();

  for (int i = 0; i < NI; ++i) {
    const int t1 = (2 * i + 1) & (NT - 1);
    const int t2 = (2 * i + 2) & (NT - 1);
    const int t3 = (2 * i + 3) & (NT - 1);
    // ---- K-tile 2i (buf0) ----
    readA32(0, 0); readB32(0, 0); stage_half(Ab, 0, 1, 1, t1); PWAIT();
    m32q<0, 0>(acc, af, bf); GBAR();
    readB32(0, 1); stage_half(Bb, 65536, 1, 0, t1); PWAIT();
    m32q<0, 1>(acc, af, bf); GBAR();
    readA32(0, 1); readB32(0, 0); stage_half(Bb, 65536, 1, 1, t1); PWAIT();
    m32q<1, 0>(acc, af, bf); GBAR();
    readB32(0, 1); stage_half(Ab, 0, 0, 0, t2); PWAITV();
    m32q<1, 1>(acc, af, bf); GBAR();
    // ---- K-tile 2i+1 (buf1) ----
    readA32(1, 0); readB32(1, 0); stage_half(Ab, 0, 0, 1, t2); PWAIT();
    m32q<0, 0>(acc, af, bf); GBAR();
    readB32(1, 1); stage_half(Bb, 65536, 0, 0, t2); PWAIT();
    m32q<0, 1>(acc, af, bf); GBAR();
    readA32(1, 1); readB32(1, 0); stage_half(Bb, 65536, 0, 1, t2); PWAIT();
    m32q<1, 0>(acc, af, bf); GBAR();
    readB32(1, 1); stage_half(Ab, 0, 1, 0, t3); PWAITV();
    m32q<1, 1>(acc, af, bf); GBAR();
  }

  const int crow = bm * 256 + wr * 128;
  const int ccol = bn * 256 + wc * 64;
#pragma unroll
  for (int mf = 0; mf < 4; ++mf)
#pragma unroll
    for (int nf = 0; nf < 2; ++nf)
#pragma unroll
      for (int r = 0; r < 16; ++r) {
        int row = crow + mf * 32 + (r & 3) + 8 * (r >> 2) + 4 * hi;
        int col = ccol + nf * 32 + lq;
        float v = acc[mf][nf][r];
        if constexpr (sizeof(OutT) == 2)
          C[(size_t)row * N + col] = f2bf(v);
        else
          C[(size_t)row * N + col] = v;
      }
}

// ---------------- flash attention (R14 exact) ----------------
__global__ __launch_bounds__(512, 4) void flash_attn(
    const u16* __restrict__ QKV, u16* __restrict__ O) {
  constexpr int S = 2048, DQ = 3072, DO = 1024;
  __shared__ u16 Kt[3][4096];
  __shared__ u16 Vt[3][4096];
  const int tid = threadIdx.x, wid = tid >> 6, lane = tid & 63;
  const int lq = lane & 31, hi = lane >> 5;

  const int id = blockIdx.x;
  const int jj0 = id >> 3;
  const int bh = (id & 7) * 8 + (jj0 >> 3), qt = jj0 & 7;
  const int b = bh >> 4, h = bh & 15;

  const size_t bq = (size_t)b * S * DQ;
  const u16* Qg = QKV + bq + h * 64;
  const u16* Kg = QKV + bq + 1024 + h * 64;
  const u16* Vg = QKV + bq + 2048 + h * 64;
  const int qrow0 = qt * 256 + wid * 32;

  const int k_kv = tid >> 3;
  const int k_col = ((tid & 7) ^ (k_kv & 7)) * 8;
  const int v_kv = ((tid >> 5) << 2) | ((tid >> 1) & 3);
  const int v_hd = (((tid >> 3) & 3) << 4) | ((tid & 1) << 3);

  bf16x8 qf[4];
#pragma unroll
  for (int kc = 0; kc < 4; ++kc)
    qf[kc] = *(const bf16x8*)&Qg[(size_t)(qrow0 + lq) * DQ + kc * 16 + hi * 8];

  f32x16 o0, o1;
#pragma unroll
  for (int r = 0; r < 16; ++r) { o0[r] = 0.f; o1[r] = 0.f; }
  float l = 0.f;

  auto stage = [&](int buf, int kv0) {
    load_lds16(Kg + (size_t)(kv0 + k_kv) * DQ + k_col, &Kt[buf][wid * 512]);
    load_lds16(Vg + (size_t)(kv0 + v_kv) * DQ + v_hd, &Vt[buf][wid * 512]);
  };

  stage(0, 0);
  stage(1, 64);
  asm volatile("s_waitcnt vmcnt(2)" ::: "memory");
  __builtin_amdgcn_s_barrier();
  asm volatile("" ::: "memory");

  int cur = 0, pre = 2;
  for (int t = 0; t < 32; ++t) {
    stage(pre, ((t + 2) & 31) * 64);

    f32x16 st[2];
#pragma unroll
    for (int blk = 0; blk < 2; ++blk) {
#pragma unroll
      for (int r = 0; r < 16; ++r) st[blk][r] = 0.f;
      bf16x8 kf[4];
#pragma unroll
      for (int kc = 0; kc < 4; ++kc) {
        int kv = blk * 32 + lq;
        int byt = kv * 128 + ((kc * 32 + hi * 16) ^ ((kv & 7) << 4));
        kf[kc] = *(const bf16x8*)((const char*)&Kt[cur][0] + byt);
      }
      __builtin_amdgcn_s_setprio(1);
#pragma unroll
      for (int kc = 0; kc < 4; ++kc)
        st[blk] = __builtin_amdgcn_mfma_f32_32x32x16_bf16(kf[kc], qf[kc], st[blk], 0, 0, 0);
      __builtin_amdgcn_s_setprio(0);
    }

    float ps = 0.f;
#pragma unroll
    for (int blk = 0; blk < 2; ++blk)
#pragma unroll
      for (int r = 0; r < 16; ++r) {
        float p = exp2_fast(st[blk][r]);
        st[blk][r] = p;
        ps += p;
      }
    l += ps;

    u32 W0[8], W1[8];
#pragma unroll
    for (int r2 = 0; r2 < 8; ++r2) {
      W0[r2] = cvt_pk_bf16(st[0][2 * r2], st[0][2 * r2 + 1]);
      W1[r2] = cvt_pk_bf16(st[1][2 * r2], st[1][2 * r2 + 1]);
    }
    bf16x8 pb[4];
#pragma unroll
    for (int ks = 0; ks < 2; ++ks) {
      u32 a0 = W0[4 * ks], a2 = W0[4 * ks + 2];
      u32 a1 = W0[4 * ks + 1], a3 = W0[4 * ks + 3];
      permlane32_swap(a0, a2);
      permlane32_swap(a1, a3);
      pb[ks] = __builtin_bit_cast(bf16x8, u32x4{a0, a1, a2, a3});
    }
#pragma unroll
    for (int ks = 0; ks < 2; ++ks) {
      u32 a0 = W1[4 * ks], a2 = W1[4 * ks + 2];
      u32 a1 = W1[4 * ks + 1], a3 = W1[4 * ks + 3];
      permlane32_swap(a0, a2);
      permlane32_swap(a1, a3);
      pb[2 + ks] = __builtin_bit_cast(bf16x8, u32x4{a0, a1, a2, a3});
    }

#pragma unroll
    for (int c2 = 0; c2 < 2; ++c2) {
      bf16x4 vh[4][2];
      const int hb = c2 * 2 + ((lane >> 4) & 1);
#pragma unroll
      for (int ks = 0; ks < 4; ++ks)
#pragma unroll
        for (int p2 = 0; p2 < 2; ++p2) {
          int a = ks * 4 + hi * 2 + p2;
          vh[ks][p2] = tr16(&Vt[cur][(a * 4 + hb) * 64 + (lane & 15) * 4]);
        }
      asm volatile("s_waitcnt lgkmcnt(0)" ::: "memory");
      __builtin_amdgcn_sched_barrier(0);
      __builtin_amdgcn_s_setprio(1);
      f32x16 oc = c2 ? o1 : o0;
#pragma unroll
      for (int ks = 0; ks < 4; ++ks) {
        bf16x8 vf = __builtin_shufflevector(vh[ks][0], vh[ks][1], 0, 1, 2, 3, 4, 5, 6, 7);
        oc = __builtin_amdgcn_mfma_f32_32x32x16_bf16(vf, pb[ks], oc, 0, 0, 0);
      }
      if (c2) o1 = oc; else o0 = oc;
      __builtin_amdgcn_s_setprio(0);
    }

    asm volatile("s_waitcnt vmcnt(2)" ::: "memory");
    __builtin_amdgcn_s_barrier();
    asm volatile("" ::: "memory");

    cur = (cur == 2) ? 0 : cur + 1;
    pre = (pre == 2) ? 0 : pre + 1;
  }

  l += __shfl_xor(l, 32);
  const float inv = 1.0f / l;
  const size_t boo = (size_t)b * S * DO + h * 64;
  const size_t qb = boo + (size_t)(qrow0 + lq) * DO;
#pragma unroll
  for (int r = 0; r < 16; ++r) {
    int hd = (r & 3) + 8 * (r >> 2) + 4 * hi;
    O[qb + hd] = f2bf(o0[r] * inv);
    O[qb + 32 + hd] = f2bf(o1[r] * inv);
  }
}

extern "C" void kernel_launch(void* const* d_in, const int* in_sizes, int n_in,
                              void* d_out, int out_size, void* d_ws, size_t ws_size,
                              hipStream_t stream) {
  const float* hs = (const float*)d_in[0];
  const float* Wq = (const float*)d_in[1];
  const float* Wk = (const float*)d_in[2];
  const float* Wv = (const float*)d_in[3];
  const float* Wo = (const float*)d_in[4];
  float* out = (float*)d_out;

  constexpr int Bn = 4, S = 2048, Dm = 1024;
  constexpr int M = Bn * S;                  // 8192
  constexpr size_t SZ = (size_t)M * Dm;
  constexpr size_t WSZ = (size_t)Dm * Dm;

  u16* wsp = (u16*)d_ws;
  u16* QKVb = wsp;                      // [M][3072] bf16 = 48 MB
  u16* hs16 = QKVb + (size_t)M * 3072;  // 16 MB
  u16* Ob = hs16;                       // alias: hs16 dead after QKV GEMM
  u16* W16 = hs16 + SZ;                 // Wq|Wk|Wv|Wo concat (contiguous)
  u16* Wo16 = W16 + 3 * WSZ;
  (void)ws_size; (void)in_sizes; (void)n_in; (void)out_size;

  // fused conversion: hs + 4 weights in one launch.
  // 1/sqrt(64) * log2(e) folded into Wq (softmax runs in base-2 domain).
  constexpr int HS4 = (int)(SZ / 4);
  constexpr int W4SEG = (int)(WSZ / 4);
  cvt_all<<<(HS4 + 4 * W4SEG) / 256, 256, 0, stream>>>(
      hs, Wq, Wk, Wv, Wo, hs16, W16, HS4, W4SEG, 0.125f * 1.44269504f);

  // fused QKV projection: [M][3072] = hs16 @ W16^T  (8-phase 256², 32x32 MFMA)
  gemm256<u16><<<(M / 256) * (3072 / 256), 512, 0, stream>>>(hs16, W16, QKVb, M, 3072, Dm);

  flash_attn<<<512, 512, 0, stream>>>(QKVb, Ob);

  // output projection (legacy 128² kernel; nwg=512 %8==0)
  gemm_bt<float><<<(M / 128) * (Dm / 128), 256, 0, stream>>>(Ob, Wo16, out, M, Dm, Dm);
}

// Round 16
// 191.581 us; speedup vs baseline: 1.0308x; 1.0308x over previous
//
#include <hip/hip_runtime.h>

using u16 = unsigned short;
using u32 = unsigned int;
typedef __attribute__((ext_vector_type(8))) short bf16x8;
typedef __attribute__((ext_vector_type(4))) short bf16x4;
typedef __attribute__((ext_vector_type(4))) float f32x4;
typedef __attribute__((ext_vector_type(16))) float f32x16;
typedef __attribute__((ext_vector_type(4))) u32 u32x4;

__device__ __forceinline__ u16 f2bf(float f) {
  u32 u = __builtin_bit_cast(u32, f);
  u += 0x7FFFu + ((u >> 16) & 1u);
  return (u16)(u >> 16);
}

__device__ __forceinline__ void load_lds16(const void* g, void* l) {
  typedef const __attribute__((address_space(1))) u32 GA;
  typedef __attribute__((address_space(3))) u32 LA;
  __builtin_amdgcn_global_load_lds((GA*)g, (LA*)l, 16, 0, 0);
}

__device__ __forceinline__ bf16x4 tr16(const u16* p) {
  typedef __attribute__((address_space(3))) const u16 LT;
  bf16x4 d;
  asm volatile("ds_read_b64_tr_b16 %0, %1" : "=v"(d) : "v"((LT*)p));
  return d;
}

__device__ __forceinline__ float exp2_fast(float x) {
  float r;
  asm("v_exp_f32 %0, %1" : "=v"(r) : "v"(x));
  return r;
}

__device__ __forceinline__ u32 cvt_pk_bf16(float lo, float hi) {
  u32 r;
  asm("v_cvt_pk_bf16_f32 %0, %1, %2" : "=v"(r) : "v"(lo), "v"(hi));
  return r;
}

__device__ __forceinline__ void permlane32_swap(u32& a, u32& b) {
  asm volatile("v_permlane32_swap_b32 %0, %1" : "+v"(a), "+v"(b));
}

// ---------------- fused f32 -> bf16 conversion (hs + 4 weights, one launch) ----
__global__ void cvt_all(const float* __restrict__ hs, const float* __restrict__ Wq,
                        const float* __restrict__ Wk, const float* __restrict__ Wv,
                        const float* __restrict__ Wo, u16* __restrict__ hs16,
                        u16* __restrict__ w16, int hs4, int w4seg, float qscale) {
  int i = blockIdx.x * blockDim.x + threadIdx.x;
  const float* src;
  u16* dst;
  float sc = 1.0f;
  int off;
  if (i < hs4) {
    src = hs; dst = hs16; off = i;
  } else {
    int j = i - hs4;
    int seg = j / w4seg;
    off = j - seg * w4seg;
    dst = w16 + (size_t)seg * (size_t)w4seg * 4;
    src = seg == 0 ? Wq : seg == 1 ? Wk : seg == 2 ? Wv : Wo;
    if (seg == 0) sc = qscale;
  }
  float4 v = reinterpret_cast<const float4*>(src)[off];
  ushort4 o;
  o.x = f2bf(v.x * sc);
  o.y = f2bf(v.y * sc);
  o.z = f2bf(v.z * sc);
  o.w = f2bf(v.w * sc);
  reinterpret_cast<ushort4*>(dst)[off] = o;
}

// ---------------- bf16 GEMM (legacy 128x128, for Wo) ----------------
template <typename OutT>
__global__ __launch_bounds__(256, 2) void gemm_bt(
    const u16* __restrict__ A, const u16* __restrict__ Bw,
    OutT* __restrict__ C, int M, int N, int K) {
  __shared__ u16 At[128 * 32];
  __shared__ u16 Bt[128 * 32];
  const int tid = threadIdx.x;
  const int wid = tid >> 6, lane = tid & 63;
  const int wr = wid >> 1, wc = wid & 1;
  const int laneR = lane & 15, laneG = lane >> 4;
  const int laneK = laneG * 8;

  const int nbm = M >> 7;
  const int cpx = gridDim.x >> 3;
  const int id = blockIdx.x;
  const int swz = (id & 7) * cpx + (id >> 3);
  const int bm = swz % nbm, bn = swz / nbm;

  f32x4 acc[4][4];
#pragma unroll
  for (int i = 0; i < 4; ++i)
#pragma unroll
    for (int j = 0; j < 4; ++j) acc[i][j] = f32x4{0.f, 0.f, 0.f, 0.f};

  const int e0 = tid * 8;
  const int r0 = e0 >> 5, c0 = e0 & 31;
  const u16* Ab = A + (size_t)(bm * 128) * K;
  const u16* Bb = Bw + (size_t)(bn * 128) * K;

  for (int k0 = 0; k0 < K; k0 += 32) {
#pragma unroll
    for (int i = 0; i < 2; ++i) {
      load_lds16(Ab + (size_t)(i * 64 + r0) * K + k0 + c0, &At[(i * 256 + wid * 64) * 8]);
      load_lds16(Bb + (size_t)(i * 64 + r0) * K + k0 + c0, &Bt[(i * 256 + wid * 64) * 8]);
    }
    __syncthreads();
    bf16x8 af[4], bfr[4];
#pragma unroll
    for (int i = 0; i < 4; ++i)
      af[i] = *(const bf16x8*)&At[(wr * 64 + i * 16 + laneR) * 32 + laneK];
#pragma unroll
    for (int j = 0; j < 4; ++j)
      bfr[j] = *(const bf16x8*)&Bt[(wc * 64 + j * 16 + laneR) * 32 + laneK];
#pragma unroll
    for (int i = 0; i < 4; ++i)
#pragma unroll
      for (int j = 0; j < 4; ++j)
        acc[i][j] = __builtin_amdgcn_mfma_f32_16x16x32_bf16(af[i], bfr[j], acc[i][j], 0, 0, 0);
    __syncthreads();
  }

  const int crow = bm * 128 + wr * 64;
  const int ccol = bn * 128 + wc * 64;
#pragma unroll
  for (int i = 0; i < 4; ++i)
#pragma unroll
    for (int j = 0; j < 4; ++j)
#pragma unroll
      for (int r = 0; r < 4; ++r) {
        int row = crow + i * 16 + laneG * 4 + r;
        int col = ccol + j * 16 + laneR;
        float v = acc[i][j][r];
        if constexpr (sizeof(OutT) == 2)
          C[(size_t)row * N + col] = f2bf(v);
        else
          C[(size_t)row * N + col] = v;
      }
}

// ---------------- 256x256 8-phase GEMM (R14/R11 exact, 16x16 MFMA) ----------------
template <int MH, int NH>
__device__ __forceinline__ void mfma_quad(f32x4 (&acc)[8][4], bf16x8 (&afr)[4][2],
                                          bf16x8 (&bfr)[2][2]) {
  __builtin_amdgcn_s_setprio(1);
#pragma unroll
  for (int m = 0; m < 4; ++m)
#pragma unroll
    for (int n = 0; n < 2; ++n)
#pragma unroll
      for (int ks = 0; ks < 2; ++ks)
        acc[MH * 4 + m][NH * 2 + n] = __builtin_amdgcn_mfma_f32_16x16x32_bf16(
            afr[m][ks], bfr[n][ks], acc[MH * 4 + m][NH * 2 + n], 0, 0, 0);
  __builtin_amdgcn_s_setprio(0);
}

#define GBAR() __builtin_amdgcn_s_barrier()
#define PWAIT()                                            \
  do {                                                     \
    GBAR();                                                \
    asm volatile("s_waitcnt lgkmcnt(0)" ::: "memory");     \
  } while (0)
#define PWAITV()                                                    \
  do {                                                              \
    GBAR();                                                         \
    asm volatile("s_waitcnt vmcnt(2) lgkmcnt(0)" ::: "memory");     \
  } while (0)

template <typename OutT>
__global__ __launch_bounds__(512, 2) void gemm256(
    const u16* __restrict__ A, const u16* __restrict__ Bw,
    OutT* __restrict__ C, int M, int N, int K) {
  __shared__ __align__(16) char ldsb[131072];
  const int tid = threadIdx.x;
  const int wid = tid >> 6, lane = tid & 63;
  const int wr = wid >> 2, wc = wid & 3;
  const int laneR = lane & 15, laneG = lane >> 4;
  const int swzR = (laneR & 7) << 4;

  const int nbm = M >> 8;
  const int cpx = gridDim.x >> 3;
  const int id = blockIdx.x;
  const int swzid = (id & 7) * cpx + (id >> 3);
  const int bm = swzid % nbm, bn = swzid / nbm;

  const u16* Ab = A + (size_t)(bm * 256) * K;
  const u16* Bb = Bw + (size_t)(bn * 256) * K;

  const int s_r = tid >> 3;
  const int s_k = ((tid & 7) ^ (s_r & 7)) * 8;

  auto stage_half = [&](const u16* Xb, int regio, int buf, int hh, int kt) {
    char* d = ldsb + regio + buf * 32768 + hh * 16384 + wid * 1024;
#pragma unroll
    for (int j = 0; j < 2; ++j)
      load_lds16(Xb + (size_t)(hh * 128 + j * 64 + s_r) * K + kt * 64 + s_k,
                 d + j * 8192);
  };
  auto rdA = [&](int buf, int mh, int m, int ks) -> bf16x8 {
    return *(const bf16x8*)(ldsb + buf * 32768 + wr * 16384 +
                            (mh * 64 + m * 16 + laneR) * 128 +
                            ((ks * 64 + laneG * 16) ^ swzR));
  };
  auto rdB = [&](int buf, int nh, int n, int ks) -> bf16x8 {
    return *(const bf16x8*)(ldsb + 65536 + buf * 32768 + (wc >> 1) * 16384 +
                            ((wc & 1) * 64 + nh * 32 + n * 16 + laneR) * 128 +
                            ((ks * 64 + laneG * 16) ^ swzR));
  };

  f32x4 acc[8][4];
#pragma unroll
  for (int i = 0; i < 8; ++i)
#pragma unroll
    for (int j = 0; j < 4; ++j) acc[i][j] = f32x4{0.f, 0.f, 0.f, 0.f};

  bf16x8 afr[4][2], bfr[2][2];
  auto readAB = [&](int buf, int mh, int nh) {
#pragma unroll
    for (int m = 0; m < 4; ++m) {
      afr[m][0] = rdA(buf, mh, m, 0);
      afr[m][1] = rdA(buf, mh, m, 1);
    }
#pragma unroll
    for (int n = 0; n < 2; ++n) {
      bfr[n][0] = rdB(buf, nh, n, 0);
      bfr[n][1] = rdB(buf, nh, n, 1);
    }
  };
  auto readB = [&](int buf, int nh) {
#pragma unroll
    for (int n = 0; n < 2; ++n) {
      bfr[n][0] = rdB(buf, nh, n, 0);
      bfr[n][1] = rdB(buf, nh, n, 1);
    }
  };

  const int NT = K >> 6, NI = K >> 7;

  stage_half(Ab, 0, 0, 0, 0);
  stage_half(Ab, 0, 0, 1, 0);
  stage_half(Bb, 65536, 0, 0, 0);
  stage_half(Bb, 65536, 0, 1, 0);
  stage_half(Ab, 0, 1, 0, 1);
  asm volatile("s_waitcnt vmcnt(2)" ::: "memory");
  GBAR();

  for (int i = 0; i < NI; ++i) {
    const int t1 = (2 * i + 1) & (NT - 1);
    const int t2 = (2 * i + 2) & (NT - 1);
    const int t3 = (2 * i + 3) & (NT - 1);
    readAB(0, 0, 0); stage_half(Ab, 0, 1, 1, t1); PWAIT();
    mfma_quad<0, 0>(acc, afr, bfr); GBAR();
    readB(0, 1); stage_half(Bb, 65536, 1, 0, t1); PWAIT();
    mfma_quad<0, 1>(acc, afr, bfr); GBAR();
    readAB(0, 1, 0); stage_half(Bb, 65536, 1, 1, t1); PWAIT();
    mfma_quad<1, 0>(acc, afr, bfr); GBAR();
    readB(0, 1); stage_half(Ab, 0, 0, 0, t2); PWAITV();
    mfma_quad<1, 1>(acc, afr, bfr); GBAR();
    readAB(1, 0, 0); stage_half(Ab, 0, 0, 1, t2); PWAIT();
    mfma_quad<0, 0>(acc, afr, bfr); GBAR();
    readB(1, 1); stage_half(Bb, 65536, 0, 0, t2); PWAIT();
    mfma_quad<0, 1>(acc, afr, bfr); GBAR();
    readAB(1, 1, 0); stage_half(Bb, 65536, 0, 1, t2); PWAIT();
    mfma_quad<1, 0>(acc, afr, bfr); GBAR();
    readB(1, 1); stage_half(Ab, 0, 1, 0, t3); PWAITV();
    mfma_quad<1, 1>(acc, afr, bfr); GBAR();
  }

  const int crow = bm * 256 + wr * 128;
  const int ccol = bn * 256 + wc * 64;
#pragma unroll
  for (int mf = 0; mf < 8; ++mf)
#pragma unroll
    for (int nf = 0; nf < 4; ++nf)
#pragma unroll
      for (int r = 0; r < 4; ++r) {
        int row = crow + mf * 16 + laneG * 4 + r;
        int col = ccol + nf * 16 + laneR;
        float v = acc[mf][nf][r];
        if constexpr (sizeof(OutT) == 2)
          C[(size_t)row * N + col] = f2bf(v);
        else
          C[(size_t)row * N + col] = v;
      }
}

// ---------------- flash attention (R14 + 4-way partial sums) ----------------
__global__ __launch_bounds__(512, 4) void flash_attn(
    const u16* __restrict__ QKV, u16* __restrict__ O) {
  constexpr int S = 2048, DQ = 3072, DO = 1024;
  __shared__ u16 Kt[3][4096];
  __shared__ u16 Vt[3][4096];
  const int tid = threadIdx.x, wid = tid >> 6, lane = tid & 63;
  const int lq = lane & 31, hi = lane >> 5;

  const int id = blockIdx.x;
  const int jj0 = id >> 3;
  const int bh = (id & 7) * 8 + (jj0 >> 3), qt = jj0 & 7;
  const int b = bh >> 4, h = bh & 15;

  const size_t bq = (size_t)b * S * DQ;
  const u16* Qg = QKV + bq + h * 64;
  const u16* Kg = QKV + bq + 1024 + h * 64;
  const u16* Vg = QKV + bq + 2048 + h * 64;
  const int qrow0 = qt * 256 + wid * 32;

  const int k_kv = tid >> 3;
  const int k_col = ((tid & 7) ^ (k_kv & 7)) * 8;
  const int v_kv = ((tid >> 5) << 2) | ((tid >> 1) & 3);
  const int v_hd = (((tid >> 3) & 3) << 4) | ((tid & 1) << 3);

  bf16x8 qf[4];
#pragma unroll
  for (int kc = 0; kc < 4; ++kc)
    qf[kc] = *(const bf16x8*)&Qg[(size_t)(qrow0 + lq) * DQ + kc * 16 + hi * 8];

  f32x16 o0, o1;
#pragma unroll
  for (int r = 0; r < 16; ++r) { o0[r] = 0.f; o1[r] = 0.f; }
  float l0 = 0.f, l1 = 0.f, l2 = 0.f, l3 = 0.f;

  auto stage = [&](int buf, int kv0) {
    load_lds16(Kg + (size_t)(kv0 + k_kv) * DQ + k_col, &Kt[buf][wid * 512]);
    load_lds16(Vg + (size_t)(kv0 + v_kv) * DQ + v_hd, &Vt[buf][wid * 512]);
  };

  stage(0, 0);
  stage(1, 64);
  asm volatile("s_waitcnt vmcnt(2)" ::: "memory");
  __builtin_amdgcn_s_barrier();
  asm volatile("" ::: "memory");

  int cur = 0, pre = 2;
  for (int t = 0; t < 32; ++t) {
    stage(pre, ((t + 2) & 31) * 64);

    f32x16 st[2];
#pragma unroll
    for (int blk = 0; blk < 2; ++blk) {
#pragma unroll
      for (int r = 0; r < 16; ++r) st[blk][r] = 0.f;
      bf16x8 kf[4];
#pragma unroll
      for (int kc = 0; kc < 4; ++kc) {
        int kv = blk * 32 + lq;
        int byt = kv * 128 + ((kc * 32 + hi * 16) ^ ((kv & 7) << 4));
        kf[kc] = *(const bf16x8*)((const char*)&Kt[cur][0] + byt);
      }
      __builtin_amdgcn_s_setprio(1);
#pragma unroll
      for (int kc = 0; kc < 4; ++kc)
        st[blk] = __builtin_amdgcn_mfma_f32_32x32x16_bf16(kf[kc], qf[kc], st[blk], 0, 0, 0);
      __builtin_amdgcn_s_setprio(0);
    }

    // 4 independent partial-sum chains (break the 32-long serial add chain)
    float p0 = 0.f, p1 = 0.f, p2 = 0.f, p3 = 0.f;
#pragma unroll
    for (int blk = 0; blk < 2; ++blk)
#pragma unroll
      for (int r = 0; r < 16; r += 4) {
        float a = exp2_fast(st[blk][r]);
        float b2 = exp2_fast(st[blk][r + 1]);
        float c = exp2_fast(st[blk][r + 2]);
        float d = exp2_fast(st[blk][r + 3]);
        st[blk][r] = a; st[blk][r + 1] = b2; st[blk][r + 2] = c; st[blk][r + 3] = d;
        p0 += a; p1 += b2; p2 += c; p3 += d;
      }
    l0 += p0; l1 += p1; l2 += p2; l3 += p3;

    u32 W0[8], W1[8];
#pragma unroll
    for (int r2 = 0; r2 < 8; ++r2) {
      W0[r2] = cvt_pk_bf16(st[0][2 * r2], st[0][2 * r2 + 1]);
      W1[r2] = cvt_pk_bf16(st[1][2 * r2], st[1][2 * r2 + 1]);
    }
    bf16x8 pb[4];
#pragma unroll
    for (int ks = 0; ks < 2; ++ks) {
      u32 a0 = W0[4 * ks], a2 = W0[4 * ks + 2];
      u32 a1 = W0[4 * ks + 1], a3 = W0[4 * ks + 3];
      permlane32_swap(a0, a2);
      permlane32_swap(a1, a3);
      pb[ks] = __builtin_bit_cast(bf16x8, u32x4{a0, a1, a2, a3});
    }
#pragma unroll
    for (int ks = 0; ks < 2; ++ks) {
      u32 a0 = W1[4 * ks], a2 = W1[4 * ks + 2];
      u32 a1 = W1[4 * ks + 1], a3 = W1[4 * ks + 3];
      permlane32_swap(a0, a2);
      permlane32_swap(a1, a3);
      pb[2 + ks] = __builtin_bit_cast(bf16x8, u32x4{a0, a1, a2, a3});
    }

#pragma unroll
    for (int c2 = 0; c2 < 2; ++c2) {
      bf16x4 vh[4][2];
      const int hb = c2 * 2 + ((lane >> 4) & 1);
#pragma unroll
      for (int ks = 0; ks < 4; ++ks)
#pragma unroll
        for (int p2x = 0; p2x < 2; ++p2x) {
          int a = ks * 4 + hi * 2 + p2x;
          vh[ks][p2x] = tr16(&Vt[cur][(a * 4 + hb) * 64 + (lane & 15) * 4]);
        }
      asm volatile("s_waitcnt lgkmcnt(0)" ::: "memory");
      __builtin_amdgcn_sched_barrier(0);
      __builtin_amdgcn_s_setprio(1);
      f32x16 oc = c2 ? o1 : o0;
#pragma unroll
      for (int ks = 0; ks < 4; ++ks) {
        bf16x8 vf = __builtin_shufflevector(vh[ks][0], vh[ks][1], 0, 1, 2, 3, 4, 5, 6, 7);
        oc = __builtin_amdgcn_mfma_f32_32x32x16_bf16(vf, pb[ks], oc, 0, 0, 0);
      }
      if (c2) o1 = oc; else o0 = oc;
      __builtin_amdgcn_s_setprio(0);
    }

    asm volatile("s_waitcnt vmcnt(2)" ::: "memory");
    __builtin_amdgcn_s_barrier();
    asm volatile("" ::: "memory");

    cur = (cur == 2) ? 0 : cur + 1;
    pre = (pre == 2) ? 0 : pre + 1;
  }

  float l = (l0 + l1) + (l2 + l3);
  l += __shfl_xor(l, 32);
  const float inv = 1.0f / l;
  const size_t boo = (size_t)b * S * DO + h * 64;
  const size_t qb = boo + (size_t)(qrow0 + lq) * DO;
#pragma unroll
  for (int r = 0; r < 16; ++r) {
    int hd = (r & 3) + 8 * (r >> 2) + 4 * hi;
    O[qb + hd] = f2bf(o0[r] * inv);
    O[qb + 32 + hd] = f2bf(o1[r] * inv);
  }
}

extern "C" void kernel_launch(void* const* d_in, const int* in_sizes, int n_in,
                              void* d_out, int out_size, void* d_ws, size_t ws_size,
                              hipStream_t stream) {
  const float* hs = (const float*)d_in[0];
  const float* Wq = (const float*)d_in[1];
  const float* Wk = (const float*)d_in[2];
  const float* Wv = (const float*)d_in[3];
  const float* Wo = (const float*)d_in[4];
  float* out = (float*)d_out;

  constexpr int Bn = 4, S = 2048, Dm = 1024;
  constexpr int M = Bn * S;                  // 8192
  constexpr size_t SZ = (size_t)M * Dm;
  constexpr size_t WSZ = (size_t)Dm * Dm;

  u16* wsp = (u16*)d_ws;
  u16* QKVb = wsp;                      // [M][3072] bf16 = 48 MB
  u16* hs16 = QKVb + (size_t)M * 3072;  // 16 MB
  u16* Ob = hs16;                       // alias: hs16 dead after QKV GEMM
  u16* W16 = hs16 + SZ;                 // Wq|Wk|Wv|Wo concat (contiguous)
  u16* Wo16 = W16 + 3 * WSZ;
  (void)ws_size; (void)in_sizes; (void)n_in; (void)out_size;

  // fused conversion: hs + 4 weights in one launch.
  // 1/sqrt(64) * log2(e) folded into Wq (softmax runs in base-2 domain).
  constexpr int HS4 = (int)(SZ / 4);
  constexpr int W4SEG = (int)(WSZ / 4);
  cvt_all<<<(HS4 + 4 * W4SEG) / 256, 256, 0, stream>>>(
      hs, Wq, Wk, Wv, Wo, hs16, W16, HS4, W4SEG, 0.125f * 1.44269504f);

  // fused QKV projection: [M][3072] = hs16 @ W16^T  (8-phase 256², 16x16 MFMA)
  gemm256<u16><<<(M / 256) * (3072 / 256), 512, 0, stream>>>(hs16, W16, QKVb, M, 3072, Dm);

  flash_attn<<<512, 512, 0, stream>>>(QKVb, Ob);

  // output projection (legacy 128² kernel; nwg=512 %8==0)
  gemm_bt<float><<<(M / 128) * (Dm / 128), 256, 0, stream>>>(Ob, Wo16, out, M, Dm, Dm);
}

// Round 17
// 189.060 us; speedup vs baseline: 1.0446x; 1.0133x over previous
//
#include <hip/hip_runtime.h>

using u16 = unsigned short;
using u32 = unsigned int;
typedef __attribute__((ext_vector_type(8))) short bf16x8;
typedef __attribute__((ext_vector_type(4))) short bf16x4;
typedef __attribute__((ext_vector_type(4))) float f32x4;
typedef __attribute__((ext_vector_type(16))) float f32x16;
typedef __attribute__((ext_vector_type(4))) u32 u32x4;

__device__ __forceinline__ u16 f2bf(float f) {
  u32 u = __builtin_bit_cast(u32, f);
  u += 0x7FFFu + ((u >> 16) & 1u);
  return (u16)(u >> 16);
}

__device__ __forceinline__ void load_lds16(const void* g, void* l) {
  typedef const __attribute__((address_space(1))) u32 GA;
  typedef __attribute__((address_space(3))) u32 LA;
  __builtin_amdgcn_global_load_lds((GA*)g, (LA*)l, 16, 0, 0);
}

__device__ __forceinline__ bf16x4 tr16(const u16* p) {
  typedef __attribute__((address_space(3))) const u16 LT;
  bf16x4 d;
  asm volatile("ds_read_b64_tr_b16 %0, %1" : "=v"(d) : "v"((LT*)p));
  return d;
}

__device__ __forceinline__ float exp2_fast(float x) {
  float r;
  asm("v_exp_f32 %0, %1" : "=v"(r) : "v"(x));
  return r;
}

__device__ __forceinline__ u32 cvt_pk_bf16(float lo, float hi) {
  u32 r;
  asm("v_cvt_pk_bf16_f32 %0, %1, %2" : "=v"(r) : "v"(lo), "v"(hi));
  return r;
}

__device__ __forceinline__ void permlane32_swap(u32& a, u32& b) {
  asm volatile("v_permlane32_swap_b32 %0, %1" : "+v"(a), "+v"(b));
}

// ---------------- fused f32 -> bf16 conversion (hs + 4 weights, one launch) ----
__global__ void cvt_all(const float* __restrict__ hs, const float* __restrict__ Wq,
                        const float* __restrict__ Wk, const float* __restrict__ Wv,
                        const float* __restrict__ Wo, u16* __restrict__ hs16,
                        u16* __restrict__ w16, int hs4, int w4seg, float qscale) {
  int i = blockIdx.x * blockDim.x + threadIdx.x;
  const float* src;
  u16* dst;
  float sc = 1.0f;
  int off;
  if (i < hs4) {
    src = hs; dst = hs16; off = i;
  } else {
    int j = i - hs4;
    int seg = j / w4seg;
    off = j - seg * w4seg;
    dst = w16 + (size_t)seg * (size_t)w4seg * 4;
    src = seg == 0 ? Wq : seg == 1 ? Wk : seg == 2 ? Wv : Wo;
    if (seg == 0) sc = qscale;
  }
  float4 v = reinterpret_cast<const float4*>(src)[off];
  ushort4 o;
  o.x = f2bf(v.x * sc);
  o.y = f2bf(v.y * sc);
  o.z = f2bf(v.z * sc);
  o.w = f2bf(v.w * sc);
  reinterpret_cast<ushort4*>(dst)[off] = o;
}

// ---------------- bf16 GEMM (legacy 128x128, for Wo) ----------------
template <typename OutT>
__global__ __launch_bounds__(256, 2) void gemm_bt(
    const u16* __restrict__ A, const u16* __restrict__ Bw,
    OutT* __restrict__ C, int M, int N, int K) {
  __shared__ u16 At[128 * 32];
  __shared__ u16 Bt[128 * 32];
  const int tid = threadIdx.x;
  const int wid = tid >> 6, lane = tid & 63;
  const int wr = wid >> 1, wc = wid & 1;
  const int laneR = lane & 15, laneG = lane >> 4;
  const int laneK = laneG * 8;

  const int nbm = M >> 7;
  const int cpx = gridDim.x >> 3;
  const int id = blockIdx.x;
  const int swz = (id & 7) * cpx + (id >> 3);
  const int bm = swz % nbm, bn = swz / nbm;

  f32x4 acc[4][4];
#pragma unroll
  for (int i = 0; i < 4; ++i)
#pragma unroll
    for (int j = 0; j < 4; ++j) acc[i][j] = f32x4{0.f, 0.f, 0.f, 0.f};

  const int e0 = tid * 8;
  const int r0 = e0 >> 5, c0 = e0 & 31;
  const u16* Ab = A + (size_t)(bm * 128) * K;
  const u16* Bb = Bw + (size_t)(bn * 128) * K;

  for (int k0 = 0; k0 < K; k0 += 32) {
#pragma unroll
    for (int i = 0; i < 2; ++i) {
      load_lds16(Ab + (size_t)(i * 64 + r0) * K + k0 + c0, &At[(i * 256 + wid * 64) * 8]);
      load_lds16(Bb + (size_t)(i * 64 + r0) * K + k0 + c0, &Bt[(i * 256 + wid * 64) * 8]);
    }
    __syncthreads();
    bf16x8 af[4], bfr[4];
#pragma unroll
    for (int i = 0; i < 4; ++i)
      af[i] = *(const bf16x8*)&At[(wr * 64 + i * 16 + laneR) * 32 + laneK];
#pragma unroll
    for (int j = 0; j < 4; ++j)
      bfr[j] = *(const bf16x8*)&Bt[(wc * 64 + j * 16 + laneR) * 32 + laneK];
#pragma unroll
    for (int i = 0; i < 4; ++i)
#pragma unroll
      for (int j = 0; j < 4; ++j)
        acc[i][j] = __builtin_amdgcn_mfma_f32_16x16x32_bf16(af[i], bfr[j], acc[i][j], 0, 0, 0);
    __syncthreads();
  }

  const int crow = bm * 128 + wr * 64;
  const int ccol = bn * 128 + wc * 64;
#pragma unroll
  for (int i = 0; i < 4; ++i)
#pragma unroll
    for (int j = 0; j < 4; ++j)
#pragma unroll
      for (int r = 0; r < 4; ++r) {
        int row = crow + i * 16 + laneG * 4 + r;
        int col = ccol + j * 16 + laneR;
        float v = acc[i][j][r];
        if constexpr (sizeof(OutT) == 2)
          C[(size_t)row * N + col] = f2bf(v);
        else
          C[(size_t)row * N + col] = v;
      }
}

// ---------------- 256x256 8-phase GEMM (R11 exact, 16x16 MFMA) ----------------
template <int MH, int NH>
__device__ __forceinline__ void mfma_quad(f32x4 (&acc)[8][4], bf16x8 (&afr)[4][2],
                                          bf16x8 (&bfr)[2][2]) {
  __builtin_amdgcn_s_setprio(1);
#pragma unroll
  for (int m = 0; m < 4; ++m)
#pragma unroll
    for (int n = 0; n < 2; ++n)
#pragma unroll
      for (int ks = 0; ks < 2; ++ks)
        acc[MH * 4 + m][NH * 2 + n] = __builtin_amdgcn_mfma_f32_16x16x32_bf16(
            afr[m][ks], bfr[n][ks], acc[MH * 4 + m][NH * 2 + n], 0, 0, 0);
  __builtin_amdgcn_s_setprio(0);
}

#define GBAR() __builtin_amdgcn_s_barrier()
#define PWAIT()                                            \
  do {                                                     \
    GBAR();                                                \
    asm volatile("s_waitcnt lgkmcnt(0)" ::: "memory");     \
  } while (0)
#define PWAITV()                                                    \
  do {                                                              \
    GBAR();                                                         \
    asm volatile("s_waitcnt vmcnt(2) lgkmcnt(0)" ::: "memory");     \
  } while (0)

template <typename OutT>
__global__ __launch_bounds__(512, 2) void gemm256(
    const u16* __restrict__ A, const u16* __restrict__ Bw,
    OutT* __restrict__ C, int M, int N, int K) {
  __shared__ __align__(16) char ldsb[131072];
  const int tid = threadIdx.x;
  const int wid = tid >> 6, lane = tid & 63;
  const int wr = wid >> 2, wc = wid & 3;
  const int laneR = lane & 15, laneG = lane >> 4;
  const int swzR = (laneR & 7) << 4;

  const int nbm = M >> 8;
  const int cpx = gridDim.x >> 3;
  const int id = blockIdx.x;
  const int swzid = (id & 7) * cpx + (id >> 3);
  const int bm = swzid % nbm, bn = swzid / nbm;

  const u16* Ab = A + (size_t)(bm * 256) * K;
  const u16* Bb = Bw + (size_t)(bn * 256) * K;

  const int s_r = tid >> 3;
  const int s_k = ((tid & 7) ^ (s_r & 7)) * 8;

  auto stage_half = [&](const u16* Xb, int regio, int buf, int hh, int kt) {
    char* d = ldsb + regio + buf * 32768 + hh * 16384 + wid * 1024;
#pragma unroll
    for (int j = 0; j < 2; ++j)
      load_lds16(Xb + (size_t)(hh * 128 + j * 64 + s_r) * K + kt * 64 + s_k,
                 d + j * 8192);
  };
  auto rdA = [&](int buf, int mh, int m, int ks) -> bf16x8 {
    return *(const bf16x8*)(ldsb + buf * 32768 + wr * 16384 +
                            (mh * 64 + m * 16 + laneR) * 128 +
                            ((ks * 64 + laneG * 16) ^ swzR));
  };
  auto rdB = [&](int buf, int nh, int n, int ks) -> bf16x8 {
    return *(const bf16x8*)(ldsb + 65536 + buf * 32768 + (wc >> 1) * 16384 +
                            ((wc & 1) * 64 + nh * 32 + n * 16 + laneR) * 128 +
                            ((ks * 64 + laneG * 16) ^ swzR));
  };

  f32x4 acc[8][4];
#pragma unroll
  for (int i = 0; i < 8; ++i)
#pragma unroll
    for (int j = 0; j < 4; ++j) acc[i][j] = f32x4{0.f, 0.f, 0.f, 0.f};

  bf16x8 afr[4][2], bfr[2][2];
  auto readAB = [&](int buf, int mh, int nh) {
#pragma unroll
    for (int m = 0; m < 4; ++m) {
      afr[m][0] = rdA(buf, mh, m, 0);
      afr[m][1] = rdA(buf, mh, m, 1);
    }
#pragma unroll
    for (int n = 0; n < 2; ++n) {
      bfr[n][0] = rdB(buf, nh, n, 0);
      bfr[n][1] = rdB(buf, nh, n, 1);
    }
  };
  auto readB = [&](int buf, int nh) {
#pragma unroll
    for (int n = 0; n < 2; ++n) {
      bfr[n][0] = rdB(buf, nh, n, 0);
      bfr[n][1] = rdB(buf, nh, n, 1);
    }
  };

  const int NT = K >> 6, NI = K >> 7;

  stage_half(Ab, 0, 0, 0, 0);
  stage_half(Ab, 0, 0, 1, 0);
  stage_half(Bb, 65536, 0, 0, 0);
  stage_half(Bb, 65536, 0, 1, 0);
  stage_half(Ab, 0, 1, 0, 1);
  asm volatile("s_waitcnt vmcnt(2)" ::: "memory");
  GBAR();

  for (int i = 0; i < NI; ++i) {
    const int t1 = (2 * i + 1) & (NT - 1);
    const int t2 = (2 * i + 2) & (NT - 1);
    const int t3 = (2 * i + 3) & (NT - 1);
    readAB(0, 0, 0); stage_half(Ab, 0, 1, 1, t1); PWAIT();
    mfma_quad<0, 0>(acc, afr, bfr); GBAR();
    readB(0, 1); stage_half(Bb, 65536, 1, 0, t1); PWAIT();
    mfma_quad<0, 1>(acc, afr, bfr); GBAR();
    readAB(0, 1, 0); stage_half(Bb, 65536, 1, 1, t1); PWAIT();
    mfma_quad<1, 0>(acc, afr, bfr); GBAR();
    readB(0, 1); stage_half(Ab, 0, 0, 0, t2); PWAITV();
    mfma_quad<1, 1>(acc, afr, bfr); GBAR();
    readAB(1, 0, 0); stage_half(Ab, 0, 0, 1, t2); PWAIT();
    mfma_quad<0, 0>(acc, afr, bfr); GBAR();
    readB(1, 1); stage_half(Bb, 65536, 0, 0, t2); PWAIT();
    mfma_quad<0, 1>(acc, afr, bfr); GBAR();
    readAB(1, 1, 0); stage_half(Bb, 65536, 0, 1, t2); PWAIT();
    mfma_quad<1, 0>(acc, afr, bfr); GBAR();
    readB(1, 1); stage_half(Ab, 0, 1, 0, t3); PWAITV();
    mfma_quad<1, 1>(acc, afr, bfr); GBAR();
  }

  const int crow = bm * 256 + wr * 128;
  const int ccol = bn * 256 + wc * 64;
#pragma unroll
  for (int mf = 0; mf < 8; ++mf)
#pragma unroll
    for (int nf = 0; nf < 4; ++nf)
#pragma unroll
      for (int r = 0; r < 4; ++r) {
        int row = crow + mf * 16 + laneG * 4 + r;
        int col = ccol + nf * 16 + laneR;
        float v = acc[mf][nf][r];
        if constexpr (sizeof(OutT) == 2)
          C[(size_t)row * N + col] = f2bf(v);
        else
          C[(size_t)row * N + col] = v;
      }
}

// ---------------- flash attention (R14 exact) ----------------
__global__ __launch_bounds__(512, 4) void flash_attn(
    const u16* __restrict__ QKV, u16* __restrict__ O) {
  constexpr int S = 2048, DQ = 3072, DO = 1024;
  __shared__ u16 Kt[3][4096];
  __shared__ u16 Vt[3][4096];
  const int tid = threadIdx.x, wid = tid >> 6, lane = tid & 63;
  const int lq = lane & 31, hi = lane >> 5;

  const int id = blockIdx.x;
  const int jj0 = id >> 3;
  const int bh = (id & 7) * 8 + (jj0 >> 3), qt = jj0 & 7;
  const int b = bh >> 4, h = bh & 15;

  const size_t bq = (size_t)b * S * DQ;
  const u16* Qg = QKV + bq + h * 64;
  const u16* Kg = QKV + bq + 1024 + h * 64;
  const u16* Vg = QKV + bq + 2048 + h * 64;
  const int qrow0 = qt * 256 + wid * 32;

  const int k_kv = tid >> 3;
  const int k_col = ((tid & 7) ^ (k_kv & 7)) * 8;
  const int v_kv = ((tid >> 5) << 2) | ((tid >> 1) & 3);
  const int v_hd = (((tid >> 3) & 3) << 4) | ((tid & 1) << 3);

  bf16x8 qf[4];
#pragma unroll
  for (int kc = 0; kc < 4; ++kc)
    qf[kc] = *(const bf16x8*)&Qg[(size_t)(qrow0 + lq) * DQ + kc * 16 + hi * 8];

  f32x16 o0, o1;
#pragma unroll
  for (int r = 0; r < 16; ++r) { o0[r] = 0.f; o1[r] = 0.f; }
  float l = 0.f;

  auto stage = [&](int buf, int kv0) {
    load_lds16(Kg + (size_t)(kv0 + k_kv) * DQ + k_col, &Kt[buf][wid * 512]);
    load_lds16(Vg + (size_t)(kv0 + v_kv) * DQ + v_hd, &Vt[buf][wid * 512]);
  };

  stage(0, 0);
  stage(1, 64);
  asm volatile("s_waitcnt vmcnt(2)" ::: "memory");
  __builtin_amdgcn_s_barrier();
  asm volatile("" ::: "memory");

  int cur = 0, pre = 2;
  for (int t = 0; t < 32; ++t) {
    stage(pre, ((t + 2) & 31) * 64);

    f32x16 st[2];
#pragma unroll
    for (int blk = 0; blk < 2; ++blk) {
#pragma unroll
      for (int r = 0; r < 16; ++r) st[blk][r] = 0.f;
      bf16x8 kf[4];
#pragma unroll
      for (int kc = 0; kc < 4; ++kc) {
        int kv = blk * 32 + lq;
        int byt = kv * 128 + ((kc * 32 + hi * 16) ^ ((kv & 7) << 4));
        kf[kc] = *(const bf16x8*)((const char*)&Kt[cur][0] + byt);
      }
      __builtin_amdgcn_s_setprio(1);
#pragma unroll
      for (int kc = 0; kc < 4; ++kc)
        st[blk] = __builtin_amdgcn_mfma_f32_32x32x16_bf16(kf[kc], qf[kc], st[blk], 0, 0, 0);
      __builtin_amdgcn_s_setprio(0);
    }

    float ps = 0.f;
#pragma unroll
    for (int blk = 0; blk < 2; ++blk)
#pragma unroll
      for (int r = 0; r < 16; ++r) {
        float p = exp2_fast(st[blk][r]);
        st[blk][r] = p;
        ps += p;
      }
    l += ps;

    u32 W0[8], W1[8];
#pragma unroll
    for (int r2 = 0; r2 < 8; ++r2) {
      W0[r2] = cvt_pk_bf16(st[0][2 * r2], st[0][2 * r2 + 1]);
      W1[r2] = cvt_pk_bf16(st[1][2 * r2], st[1][2 * r2 + 1]);
    }
    bf16x8 pb[4];
#pragma unroll
    for (int ks = 0; ks < 2; ++ks) {
      u32 a0 = W0[4 * ks], a2 = W0[4 * ks + 2];
      u32 a1 = W0[4 * ks + 1], a3 = W0[4 * ks + 3];
      permlane32_swap(a0, a2);
      permlane32_swap(a1, a3);
      pb[ks] = __builtin_bit_cast(bf16x8, u32x4{a0, a1, a2, a3});
    }
#pragma unroll
    for (int ks = 0; ks < 2; ++ks) {
      u32 a0 = W1[4 * ks], a2 = W1[4 * ks + 2];
      u32 a1 = W1[4 * ks + 1], a3 = W1[4 * ks + 3];
      permlane32_swap(a0, a2);
      permlane32_swap(a1, a3);
      pb[2 + ks] = __builtin_bit_cast(bf16x8, u32x4{a0, a1, a2, a3});
    }

#pragma unroll
    for (int c2 = 0; c2 < 2; ++c2) {
      bf16x4 vh[4][2];
      const int hb = c2 * 2 + ((lane >> 4) & 1);
#pragma unroll
      for (int ks = 0; ks < 4; ++ks)
#pragma unroll
        for (int p2 = 0; p2 < 2; ++p2) {
          int a = ks * 4 + hi * 2 + p2;
          vh[ks][p2] = tr16(&Vt[cur][(a * 4 + hb) * 64 + (lane & 15) * 4]);
        }
      asm volatile("s_waitcnt lgkmcnt(0)" ::: "memory");
      __builtin_amdgcn_sched_barrier(0);
      __builtin_amdgcn_s_setprio(1);
      f32x16 oc = c2 ? o1 : o0;
#pragma unroll
      for (int ks = 0; ks < 4; ++ks) {
        bf16x8 vf = __builtin_shufflevector(vh[ks][0], vh[ks][1], 0, 1, 2, 3, 4, 5, 6, 7);
        oc = __builtin_amdgcn_mfma_f32_32x32x16_bf16(vf, pb[ks], oc, 0, 0, 0);
      }
      if (c2) o1 = oc; else o0 = oc;
      __builtin_amdgcn_s_setprio(0);
    }

    asm volatile("s_waitcnt vmcnt(2)" ::: "memory");
    __builtin_amdgcn_s_barrier();
    asm volatile("" ::: "memory");

    cur = (cur == 2) ? 0 : cur + 1;
    pre = (pre == 2) ? 0 : pre + 1;
  }

  l += __shfl_xor(l, 32);
  const float inv = 1.0f / l;
  const size_t boo = (size_t)b * S * DO + h * 64;
  const size_t qb = boo + (size_t)(qrow0 + lq) * DO;
#pragma unroll
  for (int r = 0; r < 16; ++r) {
    int hd = (r & 3) + 8 * (r >> 2) + 4 * hi;
    O[qb + hd] = f2bf(o0[r] * inv);
    O[qb + 32 + hd] = f2bf(o1[r] * inv);
  }
}

extern "C" void kernel_launch(void* const* d_in, const int* in_sizes, int n_in,
                              void* d_out, int out_size, void* d_ws, size_t ws_size,
                              hipStream_t stream) {
  const float* hs = (const float*)d_in[0];
  const float* Wq = (const float*)d_in[1];
  const float* Wk = (const float*)d_in[2];
  const float* Wv = (const float*)d_in[3];
  const float* Wo = (const float*)d_in[4];
  float* out = (float*)d_out;

  constexpr int Bn = 4, S = 2048, Dm = 1024;
  constexpr int M = Bn * S;                  // 8192
  constexpr size_t SZ = (size_t)M * Dm;
  constexpr size_t WSZ = (size_t)Dm * Dm;

  u16* wsp = (u16*)d_ws;
  u16* QKVb = wsp;                      // [M][3072] bf16 = 48 MB
  u16* hs16 = QKVb + (size_t)M * 3072;  // 16 MB
  u16* Ob = hs16;                       // alias: hs16 dead after QKV GEMM
  u16* W16 = hs16 + SZ;                 // Wq|Wk|Wv|Wo concat (contiguous)
  u16* Wo16 = W16 + 3 * WSZ;
  (void)ws_size; (void)in_sizes; (void)n_in; (void)out_size;

  // fused conversion: hs + 4 weights in one launch.
  // 1/sqrt(64) * log2(e) folded into Wq (softmax runs in base-2 domain).
  constexpr int HS4 = (int)(SZ / 4);
  constexpr int W4SEG = (int)(WSZ / 4);
  cvt_all<<<(HS4 + 4 * W4SEG) / 256, 256, 0, stream>>>(
      hs, Wq, Wk, Wv, Wo, hs16, W16, HS4, W4SEG, 0.125f * 1.44269504f);

  // fused QKV projection: [M][3072] = hs16 @ W16^T  (8-phase 256², 16x16 MFMA)
  gemm256<u16><<<(M / 256) * (3072 / 256), 512, 0, stream>>>(hs16, W16, QKVb, M, 3072, Dm);

  flash_attn<<<512, 512, 0, stream>>>(QKVb, Ob);

  // output projection (legacy 128² kernel; nwg=512 %8==0)
  gemm_bt<float><<<(M / 128) * (Dm / 128), 256, 0, stream>>>(Ob, Wo16, out, M, Dm, Dm);
}

// Round 18
// 188.624 us; speedup vs baseline: 1.0470x; 1.0023x over previous
//
#include <hip/hip_runtime.h>

using u16 = unsigned short;
using u32 = unsigned int;
typedef __attribute__((ext_vector_type(8))) short bf16x8;
typedef __attribute__((ext_vector_type(4))) short bf16x4;
typedef __attribute__((ext_vector_type(4))) float f32x4;
typedef __attribute__((ext_vector_type(16))) float f32x16;
typedef __attribute__((ext_vector_type(4))) u32 u32x4;

__device__ __forceinline__ u16 f2bf(float f) {
  u32 u = __builtin_bit_cast(u32, f);
  u += 0x7FFFu + ((u >> 16) & 1u);
  return (u16)(u >> 16);
}

__device__ __forceinline__ void load_lds16(const void* g, void* l) {
  typedef const __attribute__((address_space(1))) u32 GA;
  typedef __attribute__((address_space(3))) u32 LA;
  __builtin_amdgcn_global_load_lds((GA*)g, (LA*)l, 16, 0, 0);
}

__device__ __forceinline__ bf16x4 tr16(const u16* p) {
  typedef __attribute__((address_space(3))) const u16 LT;
  bf16x4 d;
  asm volatile("ds_read_b64_tr_b16 %0, %1" : "=v"(d) : "v"((LT*)p));
  return d;
}

__device__ __forceinline__ float exp2_fast(float x) {
  float r;
  asm("v_exp_f32 %0, %1" : "=v"(r) : "v"(x));
  return r;
}

__device__ __forceinline__ u32 cvt_pk_bf16(float lo, float hi) {
  u32 r;
  asm("v_cvt_pk_bf16_f32 %0, %1, %2" : "=v"(r) : "v"(lo), "v"(hi));
  return r;
}

__device__ __forceinline__ void permlane32_swap(u32& a, u32& b) {
  asm volatile("v_permlane32_swap_b32 %0, %1" : "+v"(a), "+v"(b));
}

// ---------------- fused f32 -> bf16 conversion (hs + 4 weights, one launch) ----
__global__ void cvt_all(const float* __restrict__ hs, const float* __restrict__ Wq,
                        const float* __restrict__ Wk, const float* __restrict__ Wv,
                        const float* __restrict__ Wo, u16* __restrict__ hs16,
                        u16* __restrict__ w16, int hs4, int w4seg, float qscale) {
  int i = blockIdx.x * blockDim.x + threadIdx.x;
  const float* src;
  u16* dst;
  float sc = 1.0f;
  int off;
  if (i < hs4) {
    src = hs; dst = hs16; off = i;
  } else {
    int j = i - hs4;
    int seg = j / w4seg;
    off = j - seg * w4seg;
    dst = w16 + (size_t)seg * (size_t)w4seg * 4;
    src = seg == 0 ? Wq : seg == 1 ? Wk : seg == 2 ? Wv : Wo;
    if (seg == 0) sc = qscale;
  }
  float4 v = reinterpret_cast<const float4*>(src)[off];
  ushort4 o;
  o.x = f2bf(v.x * sc);
  o.y = f2bf(v.y * sc);
  o.z = f2bf(v.z * sc);
  o.w = f2bf(v.w * sc);
  reinterpret_cast<ushort4*>(dst)[off] = o;
}

// ---------------- bf16 GEMM (legacy 128x128, for Wo) ----------------
template <typename OutT>
__global__ __launch_bounds__(256, 2) void gemm_bt(
    const u16* __restrict__ A, const u16* __restrict__ Bw,
    OutT* __restrict__ C, int M, int N, int K) {
  __shared__ u16 At[128 * 32];
  __shared__ u16 Bt[128 * 32];
  const int tid = threadIdx.x;
  const int wid = tid >> 6, lane = tid & 63;
  const int wr = wid >> 1, wc = wid & 1;
  const int laneR = lane & 15, laneG = lane >> 4;
  const int laneK = laneG * 8;

  const int nbm = M >> 7;
  const int cpx = gridDim.x >> 3;
  const int id = blockIdx.x;
  const int swz = (id & 7) * cpx + (id >> 3);
  const int bm = swz % nbm, bn = swz / nbm;

  f32x4 acc[4][4];
#pragma unroll
  for (int i = 0; i < 4; ++i)
#pragma unroll
    for (int j = 0; j < 4; ++j) acc[i][j] = f32x4{0.f, 0.f, 0.f, 0.f};

  const int e0 = tid * 8;
  const int r0 = e0 >> 5, c0 = e0 & 31;
  const u16* Ab = A + (size_t)(bm * 128) * K;
  const u16* Bb = Bw + (size_t)(bn * 128) * K;

  for (int k0 = 0; k0 < K; k0 += 32) {
#pragma unroll
    for (int i = 0; i < 2; ++i) {
      load_lds16(Ab + (size_t)(i * 64 + r0) * K + k0 + c0, &At[(i * 256 + wid * 64) * 8]);
      load_lds16(Bb + (size_t)(i * 64 + r0) * K + k0 + c0, &Bt[(i * 256 + wid * 64) * 8]);
    }
    __syncthreads();
    bf16x8 af[4], bfr[4];
#pragma unroll
    for (int i = 0; i < 4; ++i)
      af[i] = *(const bf16x8*)&At[(wr * 64 + i * 16 + laneR) * 32 + laneK];
#pragma unroll
    for (int j = 0; j < 4; ++j)
      bfr[j] = *(const bf16x8*)&Bt[(wc * 64 + j * 16 + laneR) * 32 + laneK];
#pragma unroll
    for (int i = 0; i < 4; ++i)
#pragma unroll
      for (int j = 0; j < 4; ++j)
        acc[i][j] = __builtin_amdgcn_mfma_f32_16x16x32_bf16(af[i], bfr[j], acc[i][j], 0, 0, 0);
    __syncthreads();
  }

  const int crow = bm * 128 + wr * 64;
  const int ccol = bn * 128 + wc * 64;
#pragma unroll
  for (int i = 0; i < 4; ++i)
#pragma unroll
    for (int j = 0; j < 4; ++j)
#pragma unroll
      for (int r = 0; r < 4; ++r) {
        int row = crow + i * 16 + laneG * 4 + r;
        int col = ccol + j * 16 + laneR;
        float v = acc[i][j][r];
        if constexpr (sizeof(OutT) == 2)
          C[(size_t)row * N + col] = f2bf(v);
        else
          C[(size_t)row * N + col] = v;
      }
}

// ---------------- 256x256 8-phase GEMM (R11 exact, 16x16 MFMA) ----------------
template <int MH, int NH>
__device__ __forceinline__ void mfma_quad(f32x4 (&acc)[8][4], bf16x8 (&afr)[4][2],
                                          bf16x8 (&bfr)[2][2]) {
  __builtin_amdgcn_s_setprio(1);
#pragma unroll
  for (int m = 0; m < 4; ++m)
#pragma unroll
    for (int n = 0; n < 2; ++n)
#pragma unroll
      for (int ks = 0; ks < 2; ++ks)
        acc[MH * 4 + m][NH * 2 + n] = __builtin_amdgcn_mfma_f32_16x16x32_bf16(
            afr[m][ks], bfr[n][ks], acc[MH * 4 + m][NH * 2 + n], 0, 0, 0);
  __builtin_amdgcn_s_setprio(0);
}

#define GBAR() __builtin_amdgcn_s_barrier()
#define PWAIT()                                            \
  do {                                                     \
    GBAR();                                                \
    asm volatile("s_waitcnt lgkmcnt(0)" ::: "memory");     \
  } while (0)
#define PWAITV()                                                    \
  do {                                                              \
    GBAR();                                                         \
    asm volatile("s_waitcnt vmcnt(2) lgkmcnt(0)" ::: "memory");     \
  } while (0)

template <typename OutT>
__global__ __launch_bounds__(512, 2) void gemm256(
    const u16* __restrict__ A, const u16* __restrict__ Bw,
    OutT* __restrict__ C, int M, int N, int K) {
  __shared__ __align__(16) char ldsb[131072];
  const int tid = threadIdx.x;
  const int wid = tid >> 6, lane = tid & 63;
  const int wr = wid >> 2, wc = wid & 3;
  const int laneR = lane & 15, laneG = lane >> 4;
  const int swzR = (laneR & 7) << 4;

  const int nbm = M >> 8;
  const int cpx = gridDim.x >> 3;
  const int id = blockIdx.x;
  const int swzid = (id & 7) * cpx + (id >> 3);
  const int bm = swzid % nbm, bn = swzid / nbm;

  const u16* Ab = A + (size_t)(bm * 256) * K;
  const u16* Bb = Bw + (size_t)(bn * 256) * K;

  const int s_r = tid >> 3;
  const int s_k = ((tid & 7) ^ (s_r & 7)) * 8;

  auto stage_half = [&](const u16* Xb, int regio, int buf, int hh, int kt) {
    char* d = ldsb + regio + buf * 32768 + hh * 16384 + wid * 1024;
#pragma unroll
    for (int j = 0; j < 2; ++j)
      load_lds16(Xb + (size_t)(hh * 128 + j * 64 + s_r) * K + kt * 64 + s_k,
                 d + j * 8192);
  };
  auto rdA = [&](int buf, int mh, int m, int ks) -> bf16x8 {
    return *(const bf16x8*)(ldsb + buf * 32768 + wr * 16384 +
                            (mh * 64 + m * 16 + laneR) * 128 +
                            ((ks * 64 + laneG * 16) ^ swzR));
  };
  auto rdB = [&](int buf, int nh, int n, int ks) -> bf16x8 {
    return *(const bf16x8*)(ldsb + 65536 + buf * 32768 + (wc >> 1) * 16384 +
                            ((wc & 1) * 64 + nh * 32 + n * 16 + laneR) * 128 +
                            ((ks * 64 + laneG * 16) ^ swzR));
  };

  f32x4 acc[8][4];
#pragma unroll
  for (int i = 0; i < 8; ++i)
#pragma unroll
    for (int j = 0; j < 4; ++j) acc[i][j] = f32x4{0.f, 0.f, 0.f, 0.f};

  bf16x8 afr[4][2], bfr[2][2];
  auto readAB = [&](int buf, int mh, int nh) {
#pragma unroll
    for (int m = 0; m < 4; ++m) {
      afr[m][0] = rdA(buf, mh, m, 0);
      afr[m][1] = rdA(buf, mh, m, 1);
    }
#pragma unroll
    for (int n = 0; n < 2; ++n) {
      bfr[n][0] = rdB(buf, nh, n, 0);
      bfr[n][1] = rdB(buf, nh, n, 1);
    }
  };
  auto readB = [&](int buf, int nh) {
#pragma unroll
    for (int n = 0; n < 2; ++n) {
      bfr[n][0] = rdB(buf, nh, n, 0);
      bfr[n][1] = rdB(buf, nh, n, 1);
    }
  };

  const int NT = K >> 6, NI = K >> 7;

  stage_half(Ab, 0, 0, 0, 0);
  stage_half(Ab, 0, 0, 1, 0);
  stage_half(Bb, 65536, 0, 0, 0);
  stage_half(Bb, 65536, 0, 1, 0);
  stage_half(Ab, 0, 1, 0, 1);
  asm volatile("s_waitcnt vmcnt(2)" ::: "memory");
  GBAR();

  for (int i = 0; i < NI; ++i) {
    const int t1 = (2 * i + 1) & (NT - 1);
    const int t2 = (2 * i + 2) & (NT - 1);
    const int t3 = (2 * i + 3) & (NT - 1);
    readAB(0, 0, 0); stage_half(Ab, 0, 1, 1, t1); PWAIT();
    mfma_quad<0, 0>(acc, afr, bfr); GBAR();
    readB(0, 1); stage_half(Bb, 65536, 1, 0, t1); PWAIT();
    mfma_quad<0, 1>(acc, afr, bfr); GBAR();
    readAB(0, 1, 0); stage_half(Bb, 65536, 1, 1, t1); PWAIT();
    mfma_quad<1, 0>(acc, afr, bfr); GBAR();
    readB(0, 1); stage_half(Ab, 0, 0, 0, t2); PWAITV();
    mfma_quad<1, 1>(acc, afr, bfr); GBAR();
    readAB(1, 0, 0); stage_half(Ab, 0, 0, 1, t2); PWAIT();
    mfma_quad<0, 0>(acc, afr, bfr); GBAR();
    readB(1, 1); stage_half(Bb, 65536, 0, 0, t2); PWAIT();
    mfma_quad<0, 1>(acc, afr, bfr); GBAR();
    readAB(1, 1, 0); stage_half(Bb, 65536, 0, 1, t2); PWAIT();
    mfma_quad<1, 0>(acc, afr, bfr); GBAR();
    readB(1, 1); stage_half(Ab, 0, 1, 0, t3); PWAITV();
    mfma_quad<1, 1>(acc, afr, bfr); GBAR();
  }

  const int crow = bm * 256 + wr * 128;
  const int ccol = bn * 256 + wc * 64;
#pragma unroll
  for (int mf = 0; mf < 8; ++mf)
#pragma unroll
    for (int nf = 0; nf < 4; ++nf)
#pragma unroll
      for (int r = 0; r < 4; ++r) {
        int row = crow + mf * 16 + laneG * 4 + r;
        int col = ccol + nf * 16 + laneR;
        float v = acc[mf][nf][r];
        if constexpr (sizeof(OutT) == 2)
          C[(size_t)row * N + col] = f2bf(v);
        else
          C[(size_t)row * N + col] = v;
      }
}

// ---------------- flash attention (R14 body, setprio REMOVED — T5 A/B) ----------
__global__ __launch_bounds__(512, 4) void flash_attn(
    const u16* __restrict__ QKV, u16* __restrict__ O) {
  constexpr int S = 2048, DQ = 3072, DO = 1024;
  __shared__ u16 Kt[3][4096];
  __shared__ u16 Vt[3][4096];
  const int tid = threadIdx.x, wid = tid >> 6, lane = tid & 63;
  const int lq = lane & 31, hi = lane >> 5;

  const int id = blockIdx.x;
  const int jj0 = id >> 3;
  const int bh = (id & 7) * 8 + (jj0 >> 3), qt = jj0 & 7;
  const int b = bh >> 4, h = bh & 15;

  const size_t bq = (size_t)b * S * DQ;
  const u16* Qg = QKV + bq + h * 64;
  const u16* Kg = QKV + bq + 1024 + h * 64;
  const u16* Vg = QKV + bq + 2048 + h * 64;
  const int qrow0 = qt * 256 + wid * 32;

  const int k_kv = tid >> 3;
  const int k_col = ((tid & 7) ^ (k_kv & 7)) * 8;
  const int v_kv = ((tid >> 5) << 2) | ((tid >> 1) & 3);
  const int v_hd = (((tid >> 3) & 3) << 4) | ((tid & 1) << 3);

  bf16x8 qf[4];
#pragma unroll
  for (int kc = 0; kc < 4; ++kc)
    qf[kc] = *(const bf16x8*)&Qg[(size_t)(qrow0 + lq) * DQ + kc * 16 + hi * 8];

  f32x16 o0, o1;
#pragma unroll
  for (int r = 0; r < 16; ++r) { o0[r] = 0.f; o1[r] = 0.f; }
  float l = 0.f;

  auto stage = [&](int buf, int kv0) {
    load_lds16(Kg + (size_t)(kv0 + k_kv) * DQ + k_col, &Kt[buf][wid * 512]);
    load_lds16(Vg + (size_t)(kv0 + v_kv) * DQ + v_hd, &Vt[buf][wid * 512]);
  };

  stage(0, 0);
  stage(1, 64);
  asm volatile("s_waitcnt vmcnt(2)" ::: "memory");
  __builtin_amdgcn_s_barrier();
  asm volatile("" ::: "memory");

  int cur = 0, pre = 2;
  for (int t = 0; t < 32; ++t) {
    stage(pre, ((t + 2) & 31) * 64);

    f32x16 st[2];
#pragma unroll
    for (int blk = 0; blk < 2; ++blk) {
#pragma unroll
      for (int r = 0; r < 16; ++r) st[blk][r] = 0.f;
      bf16x8 kf[4];
#pragma unroll
      for (int kc = 0; kc < 4; ++kc) {
        int kv = blk * 32 + lq;
        int byt = kv * 128 + ((kc * 32 + hi * 16) ^ ((kv & 7) << 4));
        kf[kc] = *(const bf16x8*)((const char*)&Kt[cur][0] + byt);
      }
#pragma unroll
      for (int kc = 0; kc < 4; ++kc)
        st[blk] = __builtin_amdgcn_mfma_f32_32x32x16_bf16(kf[kc], qf[kc], st[blk], 0, 0, 0);
    }

    float ps = 0.f;
#pragma unroll
    for (int blk = 0; blk < 2; ++blk)
#pragma unroll
      for (int r = 0; r < 16; ++r) {
        float p = exp2_fast(st[blk][r]);
        st[blk][r] = p;
        ps += p;
      }
    l += ps;

    u32 W0[8], W1[8];
#pragma unroll
    for (int r2 = 0; r2 < 8; ++r2) {
      W0[r2] = cvt_pk_bf16(st[0][2 * r2], st[0][2 * r2 + 1]);
      W1[r2] = cvt_pk_bf16(st[1][2 * r2], st[1][2 * r2 + 1]);
    }
    bf16x8 pb[4];
#pragma unroll
    for (int ks = 0; ks < 2; ++ks) {
      u32 a0 = W0[4 * ks], a2 = W0[4 * ks + 2];
      u32 a1 = W0[4 * ks + 1], a3 = W0[4 * ks + 3];
      permlane32_swap(a0, a2);
      permlane32_swap(a1, a3);
      pb[ks] = __builtin_bit_cast(bf16x8, u32x4{a0, a1, a2, a3});
    }
#pragma unroll
    for (int ks = 0; ks < 2; ++ks) {
      u32 a0 = W1[4 * ks], a2 = W1[4 * ks + 2];
      u32 a1 = W1[4 * ks + 1], a3 = W1[4 * ks + 3];
      permlane32_swap(a0, a2);
      permlane32_swap(a1, a3);
      pb[2 + ks] = __builtin_bit_cast(bf16x8, u32x4{a0, a1, a2, a3});
    }

#pragma unroll
    for (int c2 = 0; c2 < 2; ++c2) {
      bf16x4 vh[4][2];
      const int hb = c2 * 2 + ((lane >> 4) & 1);
#pragma unroll
      for (int ks = 0; ks < 4; ++ks)
#pragma unroll
        for (int p2 = 0; p2 < 2; ++p2) {
          int a = ks * 4 + hi * 2 + p2;
          vh[ks][p2] = tr16(&Vt[cur][(a * 4 + hb) * 64 + (lane & 15) * 4]);
        }
      asm volatile("s_waitcnt lgkmcnt(0)" ::: "memory");
      __builtin_amdgcn_sched_barrier(0);
      f32x16 oc = c2 ? o1 : o0;
#pragma unroll
      for (int ks = 0; ks < 4; ++ks) {
        bf16x8 vf = __builtin_shufflevector(vh[ks][0], vh[ks][1], 0, 1, 2, 3, 4, 5, 6, 7);
        oc = __builtin_amdgcn_mfma_f32_32x32x16_bf16(vf, pb[ks], oc, 0, 0, 0);
      }
      if (c2) o1 = oc; else o0 = oc;
    }

    asm volatile("s_waitcnt vmcnt(2)" ::: "memory");
    __builtin_amdgcn_s_barrier();
    asm volatile("" ::: "memory");

    cur = (cur == 2) ? 0 : cur + 1;
    pre = (pre == 2) ? 0 : pre + 1;
  }

  l += __shfl_xor(l, 32);
  const float inv = 1.0f / l;
  const size_t boo = (size_t)b * S * DO + h * 64;
  const size_t qb = boo + (size_t)(qrow0 + lq) * DO;
#pragma unroll
  for (int r = 0; r < 16; ++r) {
    int hd = (r & 3) + 8 * (r >> 2) + 4 * hi;
    O[qb + hd] = f2bf(o0[r] * inv);
    O[qb + 32 + hd] = f2bf(o1[r] * inv);
  }
}

extern "C" void kernel_launch(void* const* d_in, const int* in_sizes, int n_in,
                              void* d_out, int out_size, void* d_ws, size_t ws_size,
                              hipStream_t stream) {
  const float* hs = (const float*)d_in[0];
  const float* Wq = (const float*)d_in[1];
  const float* Wk = (const float*)d_in[2];
  const float* Wv = (const float*)d_in[3];
  const float* Wo = (const float*)d_in[4];
  float* out = (float*)d_out;

  constexpr int Bn = 4, S = 2048, Dm = 1024;
  constexpr int M = Bn * S;                  // 8192
  constexpr size_t SZ = (size_t)M * Dm;
  constexpr size_t WSZ = (size_t)Dm * Dm;

  u16* wsp = (u16*)d_ws;
  u16* QKVb = wsp;                      // [M][3072] bf16 = 48 MB
  u16* hs16 = QKVb + (size_t)M * 3072;  // 16 MB
  u16* Ob = hs16;                       // alias: hs16 dead after QKV GEMM
  u16* W16 = hs16 + SZ;                 // Wq|Wk|Wv|Wo concat (contiguous)
  u16* Wo16 = W16 + 3 * WSZ;
  (void)ws_size; (void)in_sizes; (void)n_in; (void)out_size;

  // fused conversion: hs + 4 weights in one launch.
  // 1/sqrt(64) * log2(e) folded into Wq (softmax runs in base-2 domain).
  constexpr int HS4 = (int)(SZ / 4);
  constexpr int W4SEG = (int)(WSZ / 4);
  cvt_all<<<(HS4 + 4 * W4SEG) / 256, 256, 0, stream>>>(
      hs, Wq, Wk, Wv, Wo, hs16, W16, HS4, W4SEG, 0.125f * 1.44269504f);

  // fused QKV projection: [M][3072] = hs16 @ W16^T  (8-phase 256², 16x16 MFMA)
  gemm256<u16><<<(M / 256) * (3072 / 256), 512, 0, stream>>>(hs16, W16, QKVb, M, 3072, Dm);

  flash_attn<<<512, 512, 0, stream>>>(QKVb, Ob);

  // output projection (legacy 128² kernel; nwg=512 %8==0)
  gemm_bt<float><<<(M / 128) * (Dm / 128), 256, 0, stream>>>(Ob, Wo16, out, M, Dm, Dm);
}

// Round 19
// 185.436 us; speedup vs baseline: 1.0650x; 1.0172x over previous
//
#include <hip/hip_runtime.h>

using u16 = unsigned short;
using u32 = unsigned int;
typedef __attribute__((ext_vector_type(8))) short bf16x8;
typedef __attribute__((ext_vector_type(4))) short bf16x4;
typedef __attribute__((ext_vector_type(4))) float f32x4;
typedef __attribute__((ext_vector_type(16))) float f32x16;
typedef __attribute__((ext_vector_type(4))) u32 u32x4;

__device__ __forceinline__ u16 f2bf(float f) {
  u32 u = __builtin_bit_cast(u32, f);
  u += 0x7FFFu + ((u >> 16) & 1u);
  return (u16)(u >> 16);
}

__device__ __forceinline__ void load_lds16(const void* g, void* l) {
  typedef const __attribute__((address_space(1))) u32 GA;
  typedef __attribute__((address_space(3))) u32 LA;
  __builtin_amdgcn_global_load_lds((GA*)g, (LA*)l, 16, 0, 0);
}

__device__ __forceinline__ bf16x4 tr16(const u16* p) {
  typedef __attribute__((address_space(3))) const u16 LT;
  bf16x4 d;
  asm volatile("ds_read_b64_tr_b16 %0, %1" : "=v"(d) : "v"((LT*)p));
  return d;
}

__device__ __forceinline__ float exp2_fast(float x) {
  float r;
  asm("v_exp_f32 %0, %1" : "=v"(r) : "v"(x));
  return r;
}

__device__ __forceinline__ u32 cvt_pk_bf16(float lo, float hi) {
  u32 r;
  asm("v_cvt_pk_bf16_f32 %0, %1, %2" : "=v"(r) : "v"(lo), "v"(hi));
  return r;
}

__device__ __forceinline__ void permlane32_swap(u32& a, u32& b) {
  asm volatile("v_permlane32_swap_b32 %0, %1" : "+v"(a), "+v"(b));
}

// ---------------- fused f32 -> bf16 conversion (hs + 4 weights, one launch) ----
__global__ void cvt_all(const float* __restrict__ hs, const float* __restrict__ Wq,
                        const float* __restrict__ Wk, const float* __restrict__ Wv,
                        const float* __restrict__ Wo, u16* __restrict__ hs16,
                        u16* __restrict__ w16, int hs4, int w4seg, float qscale) {
  int i = blockIdx.x * blockDim.x + threadIdx.x;
  const float* src;
  u16* dst;
  float sc = 1.0f;
  int off;
  if (i < hs4) {
    src = hs; dst = hs16; off = i;
  } else {
    int j = i - hs4;
    int seg = j / w4seg;
    off = j - seg * w4seg;
    dst = w16 + (size_t)seg * (size_t)w4seg * 4;
    src = seg == 0 ? Wq : seg == 1 ? Wk : seg == 2 ? Wv : Wo;
    if (seg == 0) sc = qscale;
  }
  float4 v = reinterpret_cast<const float4*>(src)[off];
  ushort4 o;
  o.x = f2bf(v.x * sc);
  o.y = f2bf(v.y * sc);
  o.z = f2bf(v.z * sc);
  o.w = f2bf(v.w * sc);
  reinterpret_cast<ushort4*>(dst)[off] = o;
}

// ---------------- bf16 GEMM (legacy 128x128, for Wo) ----------------
// XCD chunk = 8bm x 8bn super-tile (A 2MB + B 2MB = L2-sized working set).
template <typename OutT>
__global__ __launch_bounds__(256, 2) void gemm_bt(
    const u16* __restrict__ A, const u16* __restrict__ Bw,
    OutT* __restrict__ C, int M, int N, int K) {
  __shared__ u16 At[128 * 32];
  __shared__ u16 Bt[128 * 32];
  const int tid = threadIdx.x;
  const int wid = tid >> 6, lane = tid & 63;
  const int wr = wid >> 1, wc = wid & 1;
  const int laneR = lane & 15, laneG = lane >> 4;
  const int laneK = laneG * 8;

  const int nbm = M >> 7;       // 64
  const int nbn = N >> 7;       // 8
  const int cpx = gridDim.x >> 3;
  const int id = blockIdx.x;
  const int swz = (id & 7) * cpx + (id >> 3);
  const int c = swz / cpx, j = swz % cpx;
  const int rpc = nbm >> 3;     // bm rows per chunk
  const int bm = c * rpc + j / nbn;
  const int bn = j % nbn;

  f32x4 acc[4][4];
#pragma unroll
  for (int i = 0; i < 4; ++i)
#pragma unroll
    for (int jj = 0; jj < 4; ++jj) acc[i][jj] = f32x4{0.f, 0.f, 0.f, 0.f};

  const int e0 = tid * 8;
  const int r0 = e0 >> 5, c0 = e0 & 31;
  const u16* Ab = A + (size_t)(bm * 128) * K;
  const u16* Bb = Bw + (size_t)(bn * 128) * K;

  for (int k0 = 0; k0 < K; k0 += 32) {
#pragma unroll
    for (int i = 0; i < 2; ++i) {
      load_lds16(Ab + (size_t)(i * 64 + r0) * K + k0 + c0, &At[(i * 256 + wid * 64) * 8]);
      load_lds16(Bb + (size_t)(i * 64 + r0) * K + k0 + c0, &Bt[(i * 256 + wid * 64) * 8]);
    }
    __syncthreads();
    bf16x8 af[4], bfr[4];
#pragma unroll
    for (int i = 0; i < 4; ++i)
      af[i] = *(const bf16x8*)&At[(wr * 64 + i * 16 + laneR) * 32 + laneK];
#pragma unroll
    for (int jj = 0; jj < 4; ++jj)
      bfr[jj] = *(const bf16x8*)&Bt[(wc * 64 + jj * 16 + laneR) * 32 + laneK];
#pragma unroll
    for (int i = 0; i < 4; ++i)
#pragma unroll
      for (int jj = 0; jj < 4; ++jj)
        acc[i][jj] = __builtin_amdgcn_mfma_f32_16x16x32_bf16(af[i], bfr[jj], acc[i][jj], 0, 0, 0);
    __syncthreads();
  }

  const int crow = bm * 128 + wr * 64;
  const int ccol = bn * 128 + wc * 64;
#pragma unroll
  for (int i = 0; i < 4; ++i)
#pragma unroll
    for (int jj = 0; jj < 4; ++jj)
#pragma unroll
      for (int r = 0; r < 4; ++r) {
        int row = crow + i * 16 + laneG * 4 + r;
        int col = ccol + jj * 16 + laneR;
        float v = acc[i][jj][r];
        if constexpr (sizeof(OutT) == 2)
          C[(size_t)row * N + col] = f2bf(v);
        else
          C[(size_t)row * N + col] = v;
      }
}

// ---------------- 256x256 8-phase GEMM (R11 schedule, 16x16 MFMA) --------------
// XCD chunk = (nbm/8)bm x nbn super-tile (A 2MB + B 6MB vs 16MB A streamed).
template <int MH, int NH>
__device__ __forceinline__ void mfma_quad(f32x4 (&acc)[8][4], bf16x8 (&afr)[4][2],
                                          bf16x8 (&bfr)[2][2]) {
  __builtin_amdgcn_s_setprio(1);
#pragma unroll
  for (int m = 0; m < 4; ++m)
#pragma unroll
    for (int n = 0; n < 2; ++n)
#pragma unroll
      for (int ks = 0; ks < 2; ++ks)
        acc[MH * 4 + m][NH * 2 + n] = __builtin_amdgcn_mfma_f32_16x16x32_bf16(
            afr[m][ks], bfr[n][ks], acc[MH * 4 + m][NH * 2 + n], 0, 0, 0);
  __builtin_amdgcn_s_setprio(0);
}

#define GBAR() __builtin_amdgcn_s_barrier()
#define PWAIT()                                            \
  do {                                                     \
    GBAR();                                                \
    asm volatile("s_waitcnt lgkmcnt(0)" ::: "memory");     \
  } while (0)
#define PWAITV()                                                    \
  do {                                                              \
    GBAR();                                                         \
    asm volatile("s_waitcnt vmcnt(2) lgkmcnt(0)" ::: "memory");     \
  } while (0)

template <typename OutT>
__global__ __launch_bounds__(512, 2) void gemm256(
    const u16* __restrict__ A, const u16* __restrict__ Bw,
    OutT* __restrict__ C, int M, int N, int K) {
  __shared__ __align__(16) char ldsb[131072];
  const int tid = threadIdx.x;
  const int wid = tid >> 6, lane = tid & 63;
  const int wr = wid >> 2, wc = wid & 3;
  const int laneR = lane & 15, laneG = lane >> 4;
  const int swzR = (laneR & 7) << 4;

  const int nbm = M >> 8;       // 32
  const int nbn = N >> 8;       // 12
  const int cpx = gridDim.x >> 3;
  const int id = blockIdx.x;
  const int swzid = (id & 7) * cpx + (id >> 3);
  const int c = swzid / cpx, j = swzid % cpx;
  const int rpc = nbm >> 3;     // bm rows per chunk (4)
  const int bm = c * rpc + j / nbn;
  const int bn = j % nbn;

  const u16* Ab = A + (size_t)(bm * 256) * K;
  const u16* Bb = Bw + (size_t)(bn * 256) * K;

  const int s_r = tid >> 3;
  const int s_k = ((tid & 7) ^ (s_r & 7)) * 8;

  auto stage_half = [&](const u16* Xb, int regio, int buf, int hh, int kt) {
    char* d = ldsb + regio + buf * 32768 + hh * 16384 + wid * 1024;
#pragma unroll
    for (int jj = 0; jj < 2; ++jj)
      load_lds16(Xb + (size_t)(hh * 128 + jj * 64 + s_r) * K + kt * 64 + s_k,
                 d + jj * 8192);
  };
  auto rdA = [&](int buf, int mh, int m, int ks) -> bf16x8 {
    return *(const bf16x8*)(ldsb + buf * 32768 + wr * 16384 +
                            (mh * 64 + m * 16 + laneR) * 128 +
                            ((ks * 64 + laneG * 16) ^ swzR));
  };
  auto rdB = [&](int buf, int nh, int n, int ks) -> bf16x8 {
    return *(const bf16x8*)(ldsb + 65536 + buf * 32768 + (wc >> 1) * 16384 +
                            ((wc & 1) * 64 + nh * 32 + n * 16 + laneR) * 128 +
                            ((ks * 64 + laneG * 16) ^ swzR));
  };

  f32x4 acc[8][4];
#pragma unroll
  for (int i = 0; i < 8; ++i)
#pragma unroll
    for (int jj = 0; jj < 4; ++jj) acc[i][jj] = f32x4{0.f, 0.f, 0.f, 0.f};

  bf16x8 afr[4][2], bfr[2][2];
  auto readAB = [&](int buf, int mh, int nh) {
#pragma unroll
    for (int m = 0; m < 4; ++m) {
      afr[m][0] = rdA(buf, mh, m, 0);
      afr[m][1] = rdA(buf, mh, m, 1);
    }
#pragma unroll
    for (int n = 0; n < 2; ++n) {
      bfr[n][0] = rdB(buf, nh, n, 0);
      bfr[n][1] = rdB(buf, nh, n, 1);
    }
  };
  auto readB = [&](int buf, int nh) {
#pragma unroll
    for (int n = 0; n < 2; ++n) {
      bfr[n][0] = rdB(buf, nh, n, 0);
      bfr[n][1] = rdB(buf, nh, n, 1);
    }
  };

  const int NT = K >> 6, NI = K >> 7;

  stage_half(Ab, 0, 0, 0, 0);
  stage_half(Ab, 0, 0, 1, 0);
  stage_half(Bb, 65536, 0, 0, 0);
  stage_half(Bb, 65536, 0, 1, 0);
  stage_half(Ab, 0, 1, 0, 1);
  asm volatile("s_waitcnt vmcnt(2)" ::: "memory");
  GBAR();

  for (int i = 0; i < NI; ++i) {
    const int t1 = (2 * i + 1) & (NT - 1);
    const int t2 = (2 * i + 2) & (NT - 1);
    const int t3 = (2 * i + 3) & (NT - 1);
    readAB(0, 0, 0); stage_half(Ab, 0, 1, 1, t1); PWAIT();
    mfma_quad<0, 0>(acc, afr, bfr); GBAR();
    readB(0, 1); stage_half(Bb, 65536, 1, 0, t1); PWAIT();
    mfma_quad<0, 1>(acc, afr, bfr); GBAR();
    readAB(0, 1, 0); stage_half(Bb, 65536, 1, 1, t1); PWAIT();
    mfma_quad<1, 0>(acc, afr, bfr); GBAR();
    readB(0, 1); stage_half(Ab, 0, 0, 0, t2); PWAITV();
    mfma_quad<1, 1>(acc, afr, bfr); GBAR();
    readAB(1, 0, 0); stage_half(Ab, 0, 0, 1, t2); PWAIT();
    mfma_quad<0, 0>(acc, afr, bfr); GBAR();
    readB(1, 1); stage_half(Bb, 65536, 0, 0, t2); PWAIT();
    mfma_quad<0, 1>(acc, afr, bfr); GBAR();
    readAB(1, 1, 0); stage_half(Bb, 65536, 0, 1, t2); PWAIT();
    mfma_quad<1, 0>(acc, afr, bfr); GBAR();
    readB(1, 1); stage_half(Ab, 0, 1, 0, t3); PWAITV();
    mfma_quad<1, 1>(acc, afr, bfr); GBAR();
  }

  const int crow = bm * 256 + wr * 128;
  const int ccol = bn * 256 + wc * 64;
#pragma unroll
  for (int mf = 0; mf < 8; ++mf)
#pragma unroll
    for (int nf = 0; nf < 4; ++nf)
#pragma unroll
      for (int r = 0; r < 4; ++r) {
        int row = crow + mf * 16 + laneG * 4 + r;
        int col = ccol + nf * 16 + laneR;
        float v = acc[mf][nf][r];
        if constexpr (sizeof(OutT) == 2)
          C[(size_t)row * N + col] = f2bf(v);
        else
          C[(size_t)row * N + col] = v;
      }
}

// ---------------- flash attention (R18 exact: R14 body, no setprio) ----------
__global__ __launch_bounds__(512, 4) void flash_attn(
    const u16* __restrict__ QKV, u16* __restrict__ O) {
  constexpr int S = 2048, DQ = 3072, DO = 1024;
  __shared__ u16 Kt[3][4096];
  __shared__ u16 Vt[3][4096];
  const int tid = threadIdx.x, wid = tid >> 6, lane = tid & 63;
  const int lq = lane & 31, hi = lane >> 5;

  const int id = blockIdx.x;
  const int jj0 = id >> 3;
  const int bh = (id & 7) * 8 + (jj0 >> 3), qt = jj0 & 7;
  const int b = bh >> 4, h = bh & 15;

  const size_t bq = (size_t)b * S * DQ;
  const u16* Qg = QKV + bq + h * 64;
  const u16* Kg = QKV + bq + 1024 + h * 64;
  const u16* Vg = QKV + bq + 2048 + h * 64;
  const int qrow0 = qt * 256 + wid * 32;

  const int k_kv = tid >> 3;
  const int k_col = ((tid & 7) ^ (k_kv & 7)) * 8;
  const int v_kv = ((tid >> 5) << 2) | ((tid >> 1) & 3);
  const int v_hd = (((tid >> 3) & 3) << 4) | ((tid & 1) << 3);

  bf16x8 qf[4];
#pragma unroll
  for (int kc = 0; kc < 4; ++kc)
    qf[kc] = *(const bf16x8*)&Qg[(size_t)(qrow0 + lq) * DQ + kc * 16 + hi * 8];

  f32x16 o0, o1;
#pragma unroll
  for (int r = 0; r < 16; ++r) { o0[r] = 0.f; o1[r] = 0.f; }
  float l = 0.f;

  auto stage = [&](int buf, int kv0) {
    load_lds16(Kg + (size_t)(kv0 + k_kv) * DQ + k_col, &Kt[buf][wid * 512]);
    load_lds16(Vg + (size_t)(kv0 + v_kv) * DQ + v_hd, &Vt[buf][wid * 512]);
  };

  stage(0, 0);
  stage(1, 64);
  asm volatile("s_waitcnt vmcnt(2)" ::: "memory");
  __builtin_amdgcn_s_barrier();
  asm volatile("" ::: "memory");

  int cur = 0, pre = 2;
  for (int t = 0; t < 32; ++t) {
    stage(pre, ((t + 2) & 31) * 64);

    f32x16 st[2];
#pragma unroll
    for (int blk = 0; blk < 2; ++blk) {
#pragma unroll
      for (int r = 0; r < 16; ++r) st[blk][r] = 0.f;
      bf16x8 kf[4];
#pragma unroll
      for (int kc = 0; kc < 4; ++kc) {
        int kv = blk * 32 + lq;
        int byt = kv * 128 + ((kc * 32 + hi * 16) ^ ((kv & 7) << 4));
        kf[kc] = *(const bf16x8*)((const char*)&Kt[cur][0] + byt);
      }
#pragma unroll
      for (int kc = 0; kc < 4; ++kc)
        st[blk] = __builtin_amdgcn_mfma_f32_32x32x16_bf16(kf[kc], qf[kc], st[blk], 0, 0, 0);
    }

    float ps = 0.f;
#pragma unroll
    for (int blk = 0; blk < 2; ++blk)
#pragma unroll
      for (int r = 0; r < 16; ++r) {
        float p = exp2_fast(st[blk][r]);
        st[blk][r] = p;
        ps += p;
      }
    l += ps;

    u32 W0[8], W1[8];
#pragma unroll
    for (int r2 = 0; r2 < 8; ++r2) {
      W0[r2] = cvt_pk_bf16(st[0][2 * r2], st[0][2 * r2 + 1]);
      W1[r2] = cvt_pk_bf16(st[1][2 * r2], st[1][2 * r2 + 1]);
    }
    bf16x8 pb[4];
#pragma unroll
    for (int ks = 0; ks < 2; ++ks) {
      u32 a0 = W0[4 * ks], a2 = W0[4 * ks + 2];
      u32 a1 = W0[4 * ks + 1], a3 = W0[4 * ks + 3];
      permlane32_swap(a0, a2);
      permlane32_swap(a1, a3);
      pb[ks] = __builtin_bit_cast(bf16x8, u32x4{a0, a1, a2, a3});
    }
#pragma unroll
    for (int ks = 0; ks < 2; ++ks) {
      u32 a0 = W1[4 * ks], a2 = W1[4 * ks + 2];
      u32 a1 = W1[4 * ks + 1], a3 = W1[4 * ks + 3];
      permlane32_swap(a0, a2);
      permlane32_swap(a1, a3);
      pb[2 + ks] = __builtin_bit_cast(bf16x8, u32x4{a0, a1, a2, a3});
    }

#pragma unroll
    for (int c2 = 0; c2 < 2; ++c2) {
      bf16x4 vh[4][2];
      const int hb = c2 * 2 + ((lane >> 4) & 1);
#pragma unroll
      for (int ks = 0; ks < 4; ++ks)
#pragma unroll
        for (int p2 = 0; p2 < 2; ++p2) {
          int a = ks * 4 + hi * 2 + p2;
          vh[ks][p2] = tr16(&Vt[cur][(a * 4 + hb) * 64 + (lane & 15) * 4]);
        }
      asm volatile("s_waitcnt lgkmcnt(0)" ::: "memory");
      __builtin_amdgcn_sched_barrier(0);
      f32x16 oc = c2 ? o1 : o0;
#pragma unroll
      for (int ks = 0; ks < 4; ++ks) {
        bf16x8 vf = __builtin_shufflevector(vh[ks][0], vh[ks][1], 0, 1, 2, 3, 4, 5, 6, 7);
        oc = __builtin_amdgcn_mfma_f32_32x32x16_bf16(vf, pb[ks], oc, 0, 0, 0);
      }
      if (c2) o1 = oc; else o0 = oc;
    }

    asm volatile("s_waitcnt vmcnt(2)" ::: "memory");
    __builtin_amdgcn_s_barrier();
    asm volatile("" ::: "memory");

    cur = (cur == 2) ? 0 : cur + 1;
    pre = (pre == 2) ? 0 : pre + 1;
  }

  l += __shfl_xor(l, 32);
  const float inv = 1.0f / l;
  const size_t boo = (size_t)b * S * DO + h * 64;
  const size_t qb = boo + (size_t)(qrow0 + lq) * DO;
#pragma unroll
  for (int r = 0; r < 16; ++r) {
    int hd = (r & 3) + 8 * (r >> 2) + 4 * hi;
    O[qb + hd] = f2bf(o0[r] * inv);
    O[qb + 32 + hd] = f2bf(o1[r] * inv);
  }
}

extern "C" void kernel_launch(void* const* d_in, const int* in_sizes, int n_in,
                              void* d_out, int out_size, void* d_ws, size_t ws_size,
                              hipStream_t stream) {
  const float* hs = (const float*)d_in[0];
  const float* Wq = (const float*)d_in[1];
  const float* Wk = (const float*)d_in[2];
  const float* Wv = (const float*)d_in[3];
  const float* Wo = (const float*)d_in[4];
  float* out = (float*)d_out;

  constexpr int Bn = 4, S = 2048, Dm = 1024;
  constexpr int M = Bn * S;                  // 8192
  constexpr size_t SZ = (size_t)M * Dm;
  constexpr size_t WSZ = (size_t)Dm * Dm;

  u16* wsp = (u16*)d_ws;
  u16* QKVb = wsp;                      // [M][3072] bf16 = 48 MB
  u16* hs16 = QKVb + (size_t)M * 3072;  // 16 MB
  u16* Ob = hs16;                       // alias: hs16 dead after QKV GEMM
  u16* W16 = hs16 + SZ;                 // Wq|Wk|Wv|Wo concat (contiguous)
  u16* Wo16 = W16 + 3 * WSZ;
  (void)ws_size; (void)in_sizes; (void)n_in; (void)out_size;

  // fused conversion: hs + 4 weights in one launch.
  // 1/sqrt(64) * log2(e) folded into Wq (softmax runs in base-2 domain).
  constexpr int HS4 = (int)(SZ / 4);
  constexpr int W4SEG = (int)(WSZ / 4);
  cvt_all<<<(HS4 + 4 * W4SEG) / 256, 256, 0, stream>>>(
      hs, Wq, Wk, Wv, Wo, hs16, W16, HS4, W4SEG, 0.125f * 1.44269504f);

  // fused QKV projection: [M][3072] = hs16 @ W16^T  (8-phase 256², super-tiled XCD chunks)
  gemm256<u16><<<(M / 256) * (3072 / 256), 512, 0, stream>>>(hs16, W16, QKVb, M, 3072, Dm);

  flash_attn<<<512, 512, 0, stream>>>(QKVb, Ob);

  // output projection (128² kernel, super-tiled XCD chunks; nwg=512 %8==0)
  gemm_bt<float><<<(M / 128) * (Dm / 128), 256, 0, stream>>>(Ob, Wo16, out, M, Dm, Dm);
}

// Round 20
// 180.797 us; speedup vs baseline: 1.0923x; 1.0257x over previous
//
#include <hip/hip_runtime.h>

using u16 = unsigned short;
using u32 = unsigned int;
typedef __attribute__((ext_vector_type(8))) short bf16x8;
typedef __attribute__((ext_vector_type(4))) short bf16x4;
typedef __attribute__((ext_vector_type(4))) float f32x4;
typedef __attribute__((ext_vector_type(16))) float f32x16;
typedef __attribute__((ext_vector_type(4))) u32 u32x4;

__device__ __forceinline__ u16 f2bf(float f) {
  u32 u = __builtin_bit_cast(u32, f);
  u += 0x7FFFu + ((u >> 16) & 1u);
  return (u16)(u >> 16);
}

__device__ __forceinline__ void load_lds16(const void* g, void* l) {
  typedef const __attribute__((address_space(1))) u32 GA;
  typedef __attribute__((address_space(3))) u32 LA;
  __builtin_amdgcn_global_load_lds((GA*)g, (LA*)l, 16, 0, 0);
}

__device__ __forceinline__ bf16x4 tr16(const u16* p) {
  typedef __attribute__((address_space(3))) const u16 LT;
  bf16x4 d;
  asm volatile("ds_read_b64_tr_b16 %0, %1" : "=v"(d) : "v"((LT*)p));
  return d;
}

__device__ __forceinline__ float exp2_fast(float x) {
  float r;
  asm("v_exp_f32 %0, %1" : "=v"(r) : "v"(x));
  return r;
}

__device__ __forceinline__ u32 cvt_pk_bf16(float lo, float hi) {
  u32 r;
  asm("v_cvt_pk_bf16_f32 %0, %1, %2" : "=v"(r) : "v"(lo), "v"(hi));
  return r;
}

__device__ __forceinline__ void permlane32_swap(u32& a, u32& b) {
  asm volatile("v_permlane32_swap_b32 %0, %1" : "+v"(a), "+v"(b));
}

// ---------------- fused f32 -> bf16 conversion (hs + 4 weights, one launch) ----
__global__ void cvt_all(const float* __restrict__ hs, const float* __restrict__ Wq,
                        const float* __restrict__ Wk, const float* __restrict__ Wv,
                        const float* __restrict__ Wo, u16* __restrict__ hs16,
                        u16* __restrict__ w16, int hs4, int w4seg, float qscale) {
  int i = blockIdx.x * blockDim.x + threadIdx.x;
  const float* src;
  u16* dst;
  float sc = 1.0f;
  int off;
  if (i < hs4) {
    src = hs; dst = hs16; off = i;
  } else {
    int j = i - hs4;
    int seg = j / w4seg;
    off = j - seg * w4seg;
    dst = w16 + (size_t)seg * (size_t)w4seg * 4;
    src = seg == 0 ? Wq : seg == 1 ? Wk : seg == 2 ? Wv : Wo;
    if (seg == 0) sc = qscale;
  }
  float4 v = reinterpret_cast<const float4*>(src)[off];
  ushort4 o;
  o.x = f2bf(v.x * sc);
  o.y = f2bf(v.y * sc);
  o.z = f2bf(v.z * sc);
  o.w = f2bf(v.w * sc);
  reinterpret_cast<ushort4*>(dst)[off] = o;
}

#define GBAR() __builtin_amdgcn_s_barrier()
#define PWAIT()                                            \
  do {                                                     \
    GBAR();                                                \
    asm volatile("s_waitcnt lgkmcnt(0)" ::: "memory");     \
  } while (0)
#define PWAITV()                                                    \
  do {                                                              \
    GBAR();                                                         \
    asm volatile("s_waitcnt vmcnt(2) lgkmcnt(0)" ::: "memory");     \
  } while (0)
#define PWAITV4()                                                   \
  do {                                                              \
    GBAR();                                                         \
    asm volatile("s_waitcnt vmcnt(4) lgkmcnt(0)" ::: "memory");     \
  } while (0)

// ---------------- 256x256 8-phase GEMM (R19 exact) ----------------
template <int MH, int NH>
__device__ __forceinline__ void mfma_quad(f32x4 (&acc)[8][4], bf16x8 (&afr)[4][2],
                                          bf16x8 (&bfr)[2][2]) {
  __builtin_amdgcn_s_setprio(1);
#pragma unroll
  for (int m = 0; m < 4; ++m)
#pragma unroll
    for (int n = 0; n < 2; ++n)
#pragma unroll
      for (int ks = 0; ks < 2; ++ks)
        acc[MH * 4 + m][NH * 2 + n] = __builtin_amdgcn_mfma_f32_16x16x32_bf16(
            afr[m][ks], bfr[n][ks], acc[MH * 4 + m][NH * 2 + n], 0, 0, 0);
  __builtin_amdgcn_s_setprio(0);
}

template <typename OutT>
__global__ __launch_bounds__(512, 2) void gemm256(
    const u16* __restrict__ A, const u16* __restrict__ Bw,
    OutT* __restrict__ C, int M, int N, int K) {
  __shared__ __align__(16) char ldsb[131072];
  const int tid = threadIdx.x;
  const int wid = tid >> 6, lane = tid & 63;
  const int wr = wid >> 2, wc = wid & 3;
  const int laneR = lane & 15, laneG = lane >> 4;
  const int swzR = (laneR & 7) << 4;

  const int nbm = M >> 8;       // 32
  const int nbn = N >> 8;       // 12
  const int cpx = gridDim.x >> 3;
  const int id = blockIdx.x;
  const int swzid = (id & 7) * cpx + (id >> 3);
  const int c = swzid / cpx, j = swzid % cpx;
  const int rpc = nbm >> 3;     // bm rows per chunk (4)
  const int bm = c * rpc + j / nbn;
  const int bn = j % nbn;

  const u16* Ab = A + (size_t)(bm * 256) * K;
  const u16* Bb = Bw + (size_t)(bn * 256) * K;

  const int s_r = tid >> 3;
  const int s_k = ((tid & 7) ^ (s_r & 7)) * 8;

  auto stage_half = [&](const u16* Xb, int regio, int buf, int hh, int kt) {
    char* d = ldsb + regio + buf * 32768 + hh * 16384 + wid * 1024;
#pragma unroll
    for (int jj = 0; jj < 2; ++jj)
      load_lds16(Xb + (size_t)(hh * 128 + jj * 64 + s_r) * K + kt * 64 + s_k,
                 d + jj * 8192);
  };
  auto rdA = [&](int buf, int mh, int m, int ks) -> bf16x8 {
    return *(const bf16x8*)(ldsb + buf * 32768 + wr * 16384 +
                            (mh * 64 + m * 16 + laneR) * 128 +
                            ((ks * 64 + laneG * 16) ^ swzR));
  };
  auto rdB = [&](int buf, int nh, int n, int ks) -> bf16x8 {
    return *(const bf16x8*)(ldsb + 65536 + buf * 32768 + (wc >> 1) * 16384 +
                            ((wc & 1) * 64 + nh * 32 + n * 16 + laneR) * 128 +
                            ((ks * 64 + laneG * 16) ^ swzR));
  };

  f32x4 acc[8][4];
#pragma unroll
  for (int i = 0; i < 8; ++i)
#pragma unroll
    for (int jj = 0; jj < 4; ++jj) acc[i][jj] = f32x4{0.f, 0.f, 0.f, 0.f};

  bf16x8 afr[4][2], bfr[2][2];
  auto readAB = [&](int buf, int mh, int nh) {
#pragma unroll
    for (int m = 0; m < 4; ++m) {
      afr[m][0] = rdA(buf, mh, m, 0);
      afr[m][1] = rdA(buf, mh, m, 1);
    }
#pragma unroll
    for (int n = 0; n < 2; ++n) {
      bfr[n][0] = rdB(buf, nh, n, 0);
      bfr[n][1] = rdB(buf, nh, n, 1);
    }
  };
  auto readB = [&](int buf, int nh) {
#pragma unroll
    for (int n = 0; n < 2; ++n) {
      bfr[n][0] = rdB(buf, nh, n, 0);
      bfr[n][1] = rdB(buf, nh, n, 1);
    }
  };

  const int NT = K >> 6, NI = K >> 7;

  stage_half(Ab, 0, 0, 0, 0);
  stage_half(Ab, 0, 0, 1, 0);
  stage_half(Bb, 65536, 0, 0, 0);
  stage_half(Bb, 65536, 0, 1, 0);
  stage_half(Ab, 0, 1, 0, 1);
  asm volatile("s_waitcnt vmcnt(2)" ::: "memory");
  GBAR();

  for (int i = 0; i < NI; ++i) {
    const int t1 = (2 * i + 1) & (NT - 1);
    const int t2 = (2 * i + 2) & (NT - 1);
    const int t3 = (2 * i + 3) & (NT - 1);
    readAB(0, 0, 0); stage_half(Ab, 0, 1, 1, t1); PWAIT();
    mfma_quad<0, 0>(acc, afr, bfr); GBAR();
    readB(0, 1); stage_half(Bb, 65536, 1, 0, t1); PWAIT();
    mfma_quad<0, 1>(acc, afr, bfr); GBAR();
    readAB(0, 1, 0); stage_half(Bb, 65536, 1, 1, t1); PWAIT();
    mfma_quad<1, 0>(acc, afr, bfr); GBAR();
    readB(0, 1); stage_half(Ab, 0, 0, 0, t2); PWAITV();
    mfma_quad<1, 1>(acc, afr, bfr); GBAR();
    readAB(1, 0, 0); stage_half(Ab, 0, 0, 1, t2); PWAIT();
    mfma_quad<0, 0>(acc, afr, bfr); GBAR();
    readB(1, 1); stage_half(Bb, 65536, 0, 0, t2); PWAIT();
    mfma_quad<0, 1>(acc, afr, bfr); GBAR();
    readAB(1, 1, 0); stage_half(Bb, 65536, 0, 1, t2); PWAIT();
    mfma_quad<1, 0>(acc, afr, bfr); GBAR();
    readB(1, 1); stage_half(Ab, 0, 1, 0, t3); PWAITV();
    mfma_quad<1, 1>(acc, afr, bfr); GBAR();
  }

  const int crow = bm * 256 + wr * 128;
  const int ccol = bn * 256 + wc * 64;
#pragma unroll
  for (int mf = 0; mf < 8; ++mf)
#pragma unroll
    for (int nf = 0; nf < 4; ++nf)
#pragma unroll
      for (int r = 0; r < 4; ++r) {
        int row = crow + mf * 16 + laneG * 4 + r;
        int col = ccol + nf * 16 + laneR;
        float v = acc[mf][nf][r];
        if constexpr (sizeof(OutT) == 2)
          C[(size_t)row * N + col] = f2bf(v);
        else
          C[(size_t)row * N + col] = v;
      }
}

// ---------------- 256x128 4-phase GEMM (R12 body + supertiled XCD chunks) ------
// For Wo: grid 32x8 = 256 blocks = 1 exact round at 1 block/CU (96 KB LDS).
// Chunk = 4bm x 8bn (A 2MB + B 2MB working set per XCD).
template <int NH>
__device__ __forceinline__ void mq(f32x4 (&acc)[4][4], bf16x8 (&afr)[4][2],
                                   bf16x8 (&bfr)[2][2]) {
  __builtin_amdgcn_s_setprio(1);
#pragma unroll
  for (int m = 0; m < 4; ++m)
#pragma unroll
    for (int n = 0; n < 2; ++n)
#pragma unroll
      for (int ks = 0; ks < 2; ++ks)
        acc[m][NH * 2 + n] = __builtin_amdgcn_mfma_f32_16x16x32_bf16(
            afr[m][ks], bfr[n][ks], acc[m][NH * 2 + n], 0, 0, 0);
  __builtin_amdgcn_s_setprio(0);
}

template <typename OutT>
__global__ __launch_bounds__(512, 2) void gemm256x128(
    const u16* __restrict__ A, const u16* __restrict__ Bw,
    OutT* __restrict__ C, int M, int N, int K) {
  __shared__ __align__(16) char ldsb[98304];
  const int tid = threadIdx.x;
  const int wid = tid >> 6, lane = tid & 63;
  const int wr = wid >> 1, wc = wid & 1;  // 4 M-waves x 2 N-waves
  const int laneR = lane & 15, laneG = lane >> 4;
  const int swzR = (laneR & 7) << 4;

  const int nbm = M >> 8;       // 32
  const int nbn = N >> 7;       // 8
  const int cpx = gridDim.x >> 3;
  const int id = blockIdx.x;
  const int swzid = (id & 7) * cpx + (id >> 3);
  const int c = swzid / cpx, j = swzid % cpx;
  const int rpc = nbm >> 3;     // 4
  const int bm = c * rpc + j / nbn;
  const int bn = j % nbn;

  const u16* Ab = A + (size_t)(bm * 256) * K;
  const u16* Bb = Bw + (size_t)(bn * 128) * K;

  const int s_r = tid >> 3;
  const int s_k = ((tid & 7) ^ (s_r & 7)) * 8;

  auto stage_unit = [&](const u16* Xb, int dstoff, int row0, int kt) {
    char* d = ldsb + dstoff + wid * 1024;
#pragma unroll
    for (int jj = 0; jj < 2; ++jj)
      load_lds16(Xb + (size_t)(row0 + jj * 64 + s_r) * K + kt * 64 + s_k,
                 d + jj * 8192);
  };
  auto rdA = [&](int buf, int m, int ks) -> bf16x8 {
    return *(const bf16x8*)(ldsb + buf * 32768 + (wr >> 1) * 16384 +
                            ((wr & 1) * 64 + m * 16 + laneR) * 128 +
                            ((ks * 64 + laneG * 16) ^ swzR));
  };
  auto rdB = [&](int buf, int nh, int n, int ks) -> bf16x8 {
    return *(const bf16x8*)(ldsb + 65536 + buf * 16384 +
                            (wc * 64 + nh * 32 + n * 16 + laneR) * 128 +
                            ((ks * 64 + laneG * 16) ^ swzR));
  };

  f32x4 acc[4][4];
#pragma unroll
  for (int i = 0; i < 4; ++i)
#pragma unroll
    for (int jj = 0; jj < 4; ++jj) acc[i][jj] = f32x4{0.f, 0.f, 0.f, 0.f};

  bf16x8 afr[4][2], bfr[2][2];
  auto readA = [&](int buf) {
#pragma unroll
    for (int m = 0; m < 4; ++m) {
      afr[m][0] = rdA(buf, m, 0);
      afr[m][1] = rdA(buf, m, 1);
    }
  };
  auto readB = [&](int buf, int nh) {
#pragma unroll
    for (int n = 0; n < 2; ++n) {
      bfr[n][0] = rdB(buf, nh, n, 0);
      bfr[n][1] = rdB(buf, nh, n, 1);
    }
  };

  const int NT = K >> 6, NI = K >> 7;

  // prologue: tile0 (3 units) -> buf0; tile1 Ah0 -> buf1; wait tile0 landed.
  stage_unit(Ab, 0, 0, 0);            // Ah0(t0)
  stage_unit(Ab, 16384, 128, 0);      // Ah1(t0)
  stage_unit(Bb, 65536, 0, 0);        // B(t0)
  stage_unit(Ab, 32768, 0, 1);        // Ah0(t1)
  asm volatile("s_waitcnt vmcnt(2)" ::: "memory");
  GBAR();

  for (int i = 0; i < NI; ++i) {
    const int tb = (2 * i + 1) & (NT - 1);
    const int tc = (2 * i + 2) & (NT - 1);
    const int td = (2 * i + 3) & (NT - 1);
    // P1: consume buf0 (A + B.nh0); stage b's last units -> buf1
    readA(0); readB(0, 0);
    stage_unit(Ab, 32768 + 16384, 128, tb);  // Ah1(b)
    stage_unit(Bb, 65536 + 16384, 0, tb);    // B(b)
    PWAIT();
    mq<0>(acc, afr, bfr); GBAR();
    // P2: consume buf0 B.nh1; stage c's A -> buf0 (A reads drained end-P1)
    readB(0, 1);
    stage_unit(Ab, 0, 0, tc);                // Ah0(c)
    stage_unit(Ab, 16384, 128, tc);          // Ah1(c)
    PWAITV4();                               // guard tile b (4 newer loads fly)
    mq<1>(acc, afr, bfr); GBAR();
    // P3: consume buf1 (A + B.nh0); stage B(c) -> buf0 (B reads drained end-P2)
    readA(1); readB(1, 0);
    stage_unit(Bb, 65536, 0, tc);            // B(c)
    PWAIT();
    mq<0>(acc, afr, bfr); GBAR();
    // P4: consume buf1 B.nh1; stage Ah0(d) -> buf1 (A reads drained end-P3)
    readB(1, 1);
    stage_unit(Ab, 32768, 0, td);            // Ah0(d)
    PWAITV();                                // guard tile c (2 newer loads fly)
    mq<1>(acc, afr, bfr); GBAR();
  }

  const int crow = bm * 256 + wr * 64;
  const int ccol = bn * 128 + wc * 64;
#pragma unroll
  for (int mf = 0; mf < 4; ++mf)
#pragma unroll
    for (int nf = 0; nf < 4; ++nf)
#pragma unroll
      for (int r = 0; r < 4; ++r) {
        int row = crow + mf * 16 + laneG * 4 + r;
        int col = ccol + nf * 16 + laneR;
        float v = acc[mf][nf][r];
        if constexpr (sizeof(OutT) == 2)
          C[(size_t)row * N + col] = f2bf(v);
        else
          C[(size_t)row * N + col] = v;
      }
}

// ---------------- flash attention (R18 exact: R14 body, no setprio) ----------
__global__ __launch_bounds__(512, 4) void flash_attn(
    const u16* __restrict__ QKV, u16* __restrict__ O) {
  constexpr int S = 2048, DQ = 3072, DO = 1024;
  __shared__ u16 Kt[3][4096];
  __shared__ u16 Vt[3][4096];
  const int tid = threadIdx.x, wid = tid >> 6, lane = tid & 63;
  const int lq = lane & 31, hi = lane >> 5;

  const int id = blockIdx.x;
  const int jj0 = id >> 3;
  const int bh = (id & 7) * 8 + (jj0 >> 3), qt = jj0 & 7;
  const int b = bh >> 4, h = bh & 15;

  const size_t bq = (size_t)b * S * DQ;
  const u16* Qg = QKV + bq + h * 64;
  const u16* Kg = QKV + bq + 1024 + h * 64;
  const u16* Vg = QKV + bq + 2048 + h * 64;
  const int qrow0 = qt * 256 + wid * 32;

  const int k_kv = tid >> 3;
  const int k_col = ((tid & 7) ^ (k_kv & 7)) * 8;
  const int v_kv = ((tid >> 5) << 2) | ((tid >> 1) & 3);
  const int v_hd = (((tid >> 3) & 3) << 4) | ((tid & 1) << 3);

  bf16x8 qf[4];
#pragma unroll
  for (int kc = 0; kc < 4; ++kc)
    qf[kc] = *(const bf16x8*)&Qg[(size_t)(qrow0 + lq) * DQ + kc * 16 + hi * 8];

  f32x16 o0, o1;
#pragma unroll
  for (int r = 0; r < 16; ++r) { o0[r] = 0.f; o1[r] = 0.f; }
  float l = 0.f;

  auto stage = [&](int buf, int kv0) {
    load_lds16(Kg + (size_t)(kv0 + k_kv) * DQ + k_col, &Kt[buf][wid * 512]);
    load_lds16(Vg + (size_t)(kv0 + v_kv) * DQ + v_hd, &Vt[buf][wid * 512]);
  };

  stage(0, 0);
  stage(1, 64);
  asm volatile("s_waitcnt vmcnt(2)" ::: "memory");
  __builtin_amdgcn_s_barrier();
  asm volatile("" ::: "memory");

  int cur = 0, pre = 2;
  for (int t = 0; t < 32; ++t) {
    stage(pre, ((t + 2) & 31) * 64);

    f32x16 st[2];
#pragma unroll
    for (int blk = 0; blk < 2; ++blk) {
#pragma unroll
      for (int r = 0; r < 16; ++r) st[blk][r] = 0.f;
      bf16x8 kf[4];
#pragma unroll
      for (int kc = 0; kc < 4; ++kc) {
        int kv = blk * 32 + lq;
        int byt = kv * 128 + ((kc * 32 + hi * 16) ^ ((kv & 7) << 4));
        kf[kc] = *(const bf16x8*)((const char*)&Kt[cur][0] + byt);
      }
#pragma unroll
      for (int kc = 0; kc < 4; ++kc)
        st[blk] = __builtin_amdgcn_mfma_f32_32x32x16_bf16(kf[kc], qf[kc], st[blk], 0, 0, 0);
    }

    float ps = 0.f;
#pragma unroll
    for (int blk = 0; blk < 2; ++blk)
#pragma unroll
      for (int r = 0; r < 16; ++r) {
        float p = exp2_fast(st[blk][r]);
        st[blk][r] = p;
        ps += p;
      }
    l += ps;

    u32 W0[8], W1[8];
#pragma unroll
    for (int r2 = 0; r2 < 8; ++r2) {
      W0[r2] = cvt_pk_bf16(st[0][2 * r2], st[0][2 * r2 + 1]);
      W1[r2] = cvt_pk_bf16(st[1][2 * r2], st[1][2 * r2 + 1]);
    }
    bf16x8 pb[4];
#pragma unroll
    for (int ks = 0; ks < 2; ++ks) {
      u32 a0 = W0[4 * ks], a2 = W0[4 * ks + 2];
      u32 a1 = W0[4 * ks + 1], a3 = W0[4 * ks + 3];
      permlane32_swap(a0, a2);
      permlane32_swap(a1, a3);
      pb[ks] = __builtin_bit_cast(bf16x8, u32x4{a0, a1, a2, a3});
    }
#pragma unroll
    for (int ks = 0; ks < 2; ++ks) {
      u32 a0 = W1[4 * ks], a2 = W1[4 * ks + 2];
      u32 a1 = W1[4 * ks + 1], a3 = W1[4 * ks + 3];
      permlane32_swap(a0, a2);
      permlane32_swap(a1, a3);
      pb[2 + ks] = __builtin_bit_cast(bf16x8, u32x4{a0, a1, a2, a3});
    }

#pragma unroll
    for (int c2 = 0; c2 < 2; ++c2) {
      bf16x4 vh[4][2];
      const int hb = c2 * 2 + ((lane >> 4) & 1);
#pragma unroll
      for (int ks = 0; ks < 4; ++ks)
#pragma unroll
        for (int p2 = 0; p2 < 2; ++p2) {
          int a = ks * 4 + hi * 2 + p2;
          vh[ks][p2] = tr16(&Vt[cur][(a * 4 + hb) * 64 + (lane & 15) * 4]);
        }
      asm volatile("s_waitcnt lgkmcnt(0)" ::: "memory");
      __builtin_amdgcn_sched_barrier(0);
      f32x16 oc = c2 ? o1 : o0;
#pragma unroll
      for (int ks = 0; ks < 4; ++ks) {
        bf16x8 vf = __builtin_shufflevector(vh[ks][0], vh[ks][1], 0, 1, 2, 3, 4, 5, 6, 7);
        oc = __builtin_amdgcn_mfma_f32_32x32x16_bf16(vf, pb[ks], oc, 0, 0, 0);
      }
      if (c2) o1 = oc; else o0 = oc;
    }

    asm volatile("s_waitcnt vmcnt(2)" ::: "memory");
    __builtin_amdgcn_s_barrier();
    asm volatile("" ::: "memory");

    cur = (cur == 2) ? 0 : cur + 1;
    pre = (pre == 2) ? 0 : pre + 1;
  }

  l += __shfl_xor(l, 32);
  const float inv = 1.0f / l;
  const size_t boo = (size_t)b * S * DO + h * 64;
  const size_t qb = boo + (size_t)(qrow0 + lq) * DO;
#pragma unroll
  for (int r = 0; r < 16; ++r) {
    int hd = (r & 3) + 8 * (r >> 2) + 4 * hi;
    O[qb + hd] = f2bf(o0[r] * inv);
    O[qb + 32 + hd] = f2bf(o1[r] * inv);
  }
}

extern "C" void kernel_launch(void* const* d_in, const int* in_sizes, int n_in,
                              void* d_out, int out_size, void* d_ws, size_t ws_size,
                              hipStream_t stream) {
  const float* hs = (const float*)d_in[0];
  const float* Wq = (const float*)d_in[1];
  const float* Wk = (const float*)d_in[2];
  const float* Wv = (const float*)d_in[3];
  const float* Wo = (const float*)d_in[4];
  float* out = (float*)d_out;

  constexpr int Bn = 4, S = 2048, Dm = 1024;
  constexpr int M = Bn * S;                  // 8192
  constexpr size_t SZ = (size_t)M * Dm;
  constexpr size_t WSZ = (size_t)Dm * Dm;

  u16* wsp = (u16*)d_ws;
  u16* QKVb = wsp;                      // [M][3072] bf16 = 48 MB
  u16* hs16 = QKVb + (size_t)M * 3072;  // 16 MB
  u16* Ob = hs16;                       // alias: hs16 dead after QKV GEMM
  u16* W16 = hs16 + SZ;                 // Wq|Wk|Wv|Wo concat (contiguous)
  u16* Wo16 = W16 + 3 * WSZ;
  (void)ws_size; (void)in_sizes; (void)n_in; (void)out_size;

  // fused conversion: hs + 4 weights in one launch.
  // 1/sqrt(64) * log2(e) folded into Wq (softmax runs in base-2 domain).
  constexpr int HS4 = (int)(SZ / 4);
  constexpr int W4SEG = (int)(WSZ / 4);
  cvt_all<<<(HS4 + 4 * W4SEG) / 256, 256, 0, stream>>>(
      hs, Wq, Wk, Wv, Wo, hs16, W16, HS4, W4SEG, 0.125f * 1.44269504f);

  // fused QKV projection: [M][3072] = hs16 @ W16^T  (8-phase 256², super-tiled XCD chunks)
  gemm256<u16><<<(M / 256) * (3072 / 256), 512, 0, stream>>>(hs16, W16, QKVb, M, 3072, Dm);

  flash_attn<<<512, 512, 0, stream>>>(QKVb, Ob);

  // output projection: 4-phase 256x128, grid 256 = exactly 1 round, supertiled chunks
  gemm256x128<float><<<(M / 256) * (Dm / 128), 512, 0, stream>>>(Ob, Wo16, out, M, Dm, Dm);
}

// Round 21
// 178.103 us; speedup vs baseline: 1.1088x; 1.0151x over previous
//
#include <hip/hip_runtime.h>

using u16 = unsigned short;
using u32 = unsigned int;
typedef __attribute__((ext_vector_type(8))) short bf16x8;
typedef __attribute__((ext_vector_type(4))) short bf16x4;
typedef __attribute__((ext_vector_type(4))) float f32x4;
typedef __attribute__((ext_vector_type(16))) float f32x16;
typedef __attribute__((ext_vector_type(4))) u32 u32x4;

__device__ __forceinline__ u16 f2bf(float f) {
  u32 u = __builtin_bit_cast(u32, f);
  u += 0x7FFFu + ((u >> 16) & 1u);
  return (u16)(u >> 16);
}

__device__ __forceinline__ void load_lds16(const void* g, void* l) {
  typedef const __attribute__((address_space(1))) u32 GA;
  typedef __attribute__((address_space(3))) u32 LA;
  __builtin_amdgcn_global_load_lds((GA*)g, (LA*)l, 16, 0, 0);
}

__device__ __forceinline__ bf16x4 tr16(const u16* p) {
  typedef __attribute__((address_space(3))) const u16 LT;
  bf16x4 d;
  asm volatile("ds_read_b64_tr_b16 %0, %1" : "=v"(d) : "v"((LT*)p));
  return d;
}

__device__ __forceinline__ float exp2_fast(float x) {
  float r;
  asm("v_exp_f32 %0, %1" : "=v"(r) : "v"(x));
  return r;
}

__device__ __forceinline__ u32 cvt_pk_bf16(float lo, float hi) {
  u32 r;
  asm("v_cvt_pk_bf16_f32 %0, %1, %2" : "=v"(r) : "v"(lo), "v"(hi));
  return r;
}

__device__ __forceinline__ void permlane32_swap(u32& a, u32& b) {
  asm volatile("v_permlane32_swap_b32 %0, %1" : "+v"(a), "+v"(b));
}

// ---------------- fused f32 -> bf16 conversion (hs + 4 weights, one launch) ----
__global__ void cvt_all(const float* __restrict__ hs, const float* __restrict__ Wq,
                        const float* __restrict__ Wk, const float* __restrict__ Wv,
                        const float* __restrict__ Wo, u16* __restrict__ hs16,
                        u16* __restrict__ w16, int hs4, int w4seg, float qscale) {
  int i = blockIdx.x * blockDim.x + threadIdx.x;
  const float* src;
  u16* dst;
  float sc = 1.0f;
  int off;
  if (i < hs4) {
    src = hs; dst = hs16; off = i;
  } else {
    int j = i - hs4;
    int seg = j / w4seg;
    off = j - seg * w4seg;
    dst = w16 + (size_t)seg * (size_t)w4seg * 4;
    src = seg == 0 ? Wq : seg == 1 ? Wk : seg == 2 ? Wv : Wo;
    if (seg == 0) sc = qscale;
  }
  float4 v = reinterpret_cast<const float4*>(src)[off];
  ushort4 o;
  o.x = f2bf(v.x * sc);
  o.y = f2bf(v.y * sc);
  o.z = f2bf(v.z * sc);
  o.w = f2bf(v.w * sc);
  reinterpret_cast<ushort4*>(dst)[off] = o;
}

#define GBAR() __builtin_amdgcn_s_barrier()
#define PWAIT()                                            \
  do {                                                     \
    GBAR();                                                \
    asm volatile("s_waitcnt lgkmcnt(0)" ::: "memory");     \
  } while (0)
#define PWAITV()                                                    \
  do {                                                              \
    GBAR();                                                         \
    asm volatile("s_waitcnt vmcnt(2) lgkmcnt(0)" ::: "memory");     \
  } while (0)
#define PWAITV4()                                                   \
  do {                                                              \
    GBAR();                                                         \
    asm volatile("s_waitcnt vmcnt(4) lgkmcnt(0)" ::: "memory");     \
  } while (0)

// ---------------- 256x256 8-phase GEMM (R19 exact; kept for fallback) ----------
template <int MH, int NH>
__device__ __forceinline__ void mfma_quad(f32x4 (&acc)[8][4], bf16x8 (&afr)[4][2],
                                          bf16x8 (&bfr)[2][2]) {
  __builtin_amdgcn_s_setprio(1);
#pragma unroll
  for (int m = 0; m < 4; ++m)
#pragma unroll
    for (int n = 0; n < 2; ++n)
#pragma unroll
      for (int ks = 0; ks < 2; ++ks)
        acc[MH * 4 + m][NH * 2 + n] = __builtin_amdgcn_mfma_f32_16x16x32_bf16(
            afr[m][ks], bfr[n][ks], acc[MH * 4 + m][NH * 2 + n], 0, 0, 0);
  __builtin_amdgcn_s_setprio(0);
}

template <typename OutT>
__global__ __launch_bounds__(512, 2) void gemm256(
    const u16* __restrict__ A, const u16* __restrict__ Bw,
    OutT* __restrict__ C, int M, int N, int K) {
  __shared__ __align__(16) char ldsb[131072];
  const int tid = threadIdx.x;
  const int wid = tid >> 6, lane = tid & 63;
  const int wr = wid >> 2, wc = wid & 3;
  const int laneR = lane & 15, laneG = lane >> 4;
  const int swzR = (laneR & 7) << 4;

  const int nbm = M >> 8;
  const int nbn = N >> 8;
  const int cpx = gridDim.x >> 3;
  const int id = blockIdx.x;
  const int swzid = (id & 7) * cpx + (id >> 3);
  const int c = swzid / cpx, j = swzid % cpx;
  const int rpc = nbm >> 3;
  const int bm = c * rpc + j / nbn;
  const int bn = j % nbn;

  const u16* Ab = A + (size_t)(bm * 256) * K;
  const u16* Bb = Bw + (size_t)(bn * 256) * K;

  const int s_r = tid >> 3;
  const int s_k = ((tid & 7) ^ (s_r & 7)) * 8;

  auto stage_half = [&](const u16* Xb, int regio, int buf, int hh, int kt) {
    char* d = ldsb + regio + buf * 32768 + hh * 16384 + wid * 1024;
#pragma unroll
    for (int jj = 0; jj < 2; ++jj)
      load_lds16(Xb + (size_t)(hh * 128 + jj * 64 + s_r) * K + kt * 64 + s_k,
                 d + jj * 8192);
  };
  auto rdA = [&](int buf, int mh, int m, int ks) -> bf16x8 {
    return *(const bf16x8*)(ldsb + buf * 32768 + wr * 16384 +
                            (mh * 64 + m * 16 + laneR) * 128 +
                            ((ks * 64 + laneG * 16) ^ swzR));
  };
  auto rdB = [&](int buf, int nh, int n, int ks) -> bf16x8 {
    return *(const bf16x8*)(ldsb + 65536 + buf * 32768 + (wc >> 1) * 16384 +
                            ((wc & 1) * 64 + nh * 32 + n * 16 + laneR) * 128 +
                            ((ks * 64 + laneG * 16) ^ swzR));
  };

  f32x4 acc[8][4];
#pragma unroll
  for (int i = 0; i < 8; ++i)
#pragma unroll
    for (int jj = 0; jj < 4; ++jj) acc[i][jj] = f32x4{0.f, 0.f, 0.f, 0.f};

  bf16x8 afr[4][2], bfr[2][2];
  auto readAB = [&](int buf, int mh, int nh) {
#pragma unroll
    for (int m = 0; m < 4; ++m) {
      afr[m][0] = rdA(buf, mh, m, 0);
      afr[m][1] = rdA(buf, mh, m, 1);
    }
#pragma unroll
    for (int n = 0; n < 2; ++n) {
      bfr[n][0] = rdB(buf, nh, n, 0);
      bfr[n][1] = rdB(buf, nh, n, 1);
    }
  };
  auto readB = [&](int buf, int nh) {
#pragma unroll
    for (int n = 0; n < 2; ++n) {
      bfr[n][0] = rdB(buf, nh, n, 0);
      bfr[n][1] = rdB(buf, nh, n, 1);
    }
  };

  const int NT = K >> 6, NI = K >> 7;

  stage_half(Ab, 0, 0, 0, 0);
  stage_half(Ab, 0, 0, 1, 0);
  stage_half(Bb, 65536, 0, 0, 0);
  stage_half(Bb, 65536, 0, 1, 0);
  stage_half(Ab, 0, 1, 0, 1);
  asm volatile("s_waitcnt vmcnt(2)" ::: "memory");
  GBAR();

  for (int i = 0; i < NI; ++i) {
    const int t1 = (2 * i + 1) & (NT - 1);
    const int t2 = (2 * i + 2) & (NT - 1);
    const int t3 = (2 * i + 3) & (NT - 1);
    readAB(0, 0, 0); stage_half(Ab, 0, 1, 1, t1); PWAIT();
    mfma_quad<0, 0>(acc, afr, bfr); GBAR();
    readB(0, 1); stage_half(Bb, 65536, 1, 0, t1); PWAIT();
    mfma_quad<0, 1>(acc, afr, bfr); GBAR();
    readAB(0, 1, 0); stage_half(Bb, 65536, 1, 1, t1); PWAIT();
    mfma_quad<1, 0>(acc, afr, bfr); GBAR();
    readB(0, 1); stage_half(Ab, 0, 0, 0, t2); PWAITV();
    mfma_quad<1, 1>(acc, afr, bfr); GBAR();
    readAB(1, 0, 0); stage_half(Ab, 0, 0, 1, t2); PWAIT();
    mfma_quad<0, 0>(acc, afr, bfr); GBAR();
    readB(1, 1); stage_half(Bb, 65536, 0, 0, t2); PWAIT();
    mfma_quad<0, 1>(acc, afr, bfr); GBAR();
    readAB(1, 1, 0); stage_half(Bb, 65536, 0, 1, t2); PWAIT();
    mfma_quad<1, 0>(acc, afr, bfr); GBAR();
    readB(1, 1); stage_half(Ab, 0, 1, 0, t3); PWAITV();
    mfma_quad<1, 1>(acc, afr, bfr); GBAR();
  }

  const int crow = bm * 256 + wr * 128;
  const int ccol = bn * 256 + wc * 64;
#pragma unroll
  for (int mf = 0; mf < 8; ++mf)
#pragma unroll
    for (int nf = 0; nf < 4; ++nf)
#pragma unroll
      for (int r = 0; r < 4; ++r) {
        int row = crow + mf * 16 + laneG * 4 + r;
        int col = ccol + nf * 16 + laneR;
        float v = acc[mf][nf][r];
        if constexpr (sizeof(OutT) == 2)
          C[(size_t)row * N + col] = f2bf(v);
        else
          C[(size_t)row * N + col] = v;
      }
}

// ---------------- 256x128 4-phase GEMM (R20 body + generalized chunks) ---------
// Chunk geometry (rpc bm-rows x nbnc bn-cols per XCD chunk) passed at launch:
//   QKV (N=3072): rpc=8, nbnc=12 -> concurrent footprint A 1.5MB + B 3MB ~ L2.
//   Wo  (N=1024): rpc=4, nbnc=8  -> A 2MB + B 2MB (R20-proven).
template <int NH>
__device__ __forceinline__ void mq(f32x4 (&acc)[4][4], bf16x8 (&afr)[4][2],
                                   bf16x8 (&bfr)[2][2]) {
  __builtin_amdgcn_s_setprio(1);
#pragma unroll
  for (int m = 0; m < 4; ++m)
#pragma unroll
    for (int n = 0; n < 2; ++n)
#pragma unroll
      for (int ks = 0; ks < 2; ++ks)
        acc[m][NH * 2 + n] = __builtin_amdgcn_mfma_f32_16x16x32_bf16(
            afr[m][ks], bfr[n][ks], acc[m][NH * 2 + n], 0, 0, 0);
  __builtin_amdgcn_s_setprio(0);
}

template <typename OutT>
__global__ __launch_bounds__(512, 2) void gemm256x128(
    const u16* __restrict__ A, const u16* __restrict__ Bw,
    OutT* __restrict__ C, int M, int N, int K, int rpc, int nbnc) {
  __shared__ __align__(16) char ldsb[98304];
  const int tid = threadIdx.x;
  const int wid = tid >> 6, lane = tid & 63;
  const int wr = wid >> 1, wc = wid & 1;  // 4 M-waves x 2 N-waves
  const int laneR = lane & 15, laneG = lane >> 4;
  const int swzR = (laneR & 7) << 4;

  const int nbn = N >> 7;
  const int cpx = gridDim.x >> 3;
  const int id = blockIdx.x;
  const int swzid = (id & 7) * cpx + (id >> 3);
  const int c = swzid / cpx, j = swzid % cpx;
  const int ncc = nbn / nbnc;           // chunk-grid columns
  const int chunk_row = c / ncc, chunk_col = c % ncc;
  const int bm = chunk_row * rpc + j / nbnc;
  const int bn = chunk_col * nbnc + j % nbnc;

  const u16* Ab = A + (size_t)(bm * 256) * K;
  const u16* Bb = Bw + (size_t)(bn * 128) * K;

  const int s_r = tid >> 3;
  const int s_k = ((tid & 7) ^ (s_r & 7)) * 8;

  auto stage_unit = [&](const u16* Xb, int dstoff, int row0, int kt) {
    char* d = ldsb + dstoff + wid * 1024;
#pragma unroll
    for (int jj = 0; jj < 2; ++jj)
      load_lds16(Xb + (size_t)(row0 + jj * 64 + s_r) * K + kt * 64 + s_k,
                 d + jj * 8192);
  };
  auto rdA = [&](int buf, int m, int ks) -> bf16x8 {
    return *(const bf16x8*)(ldsb + buf * 32768 + (wr >> 1) * 16384 +
                            ((wr & 1) * 64 + m * 16 + laneR) * 128 +
                            ((ks * 64 + laneG * 16) ^ swzR));
  };
  auto rdB = [&](int buf, int nh, int n, int ks) -> bf16x8 {
    return *(const bf16x8*)(ldsb + 65536 + buf * 16384 +
                            (wc * 64 + nh * 32 + n * 16 + laneR) * 128 +
                            ((ks * 64 + laneG * 16) ^ swzR));
  };

  f32x4 acc[4][4];
#pragma unroll
  for (int i = 0; i < 4; ++i)
#pragma unroll
    for (int jj = 0; jj < 4; ++jj) acc[i][jj] = f32x4{0.f, 0.f, 0.f, 0.f};

  bf16x8 afr[4][2], bfr[2][2];
  auto readA = [&](int buf) {
#pragma unroll
    for (int m = 0; m < 4; ++m) {
      afr[m][0] = rdA(buf, m, 0);
      afr[m][1] = rdA(buf, m, 1);
    }
  };
  auto readB = [&](int buf, int nh) {
#pragma unroll
    for (int n = 0; n < 2; ++n) {
      bfr[n][0] = rdB(buf, nh, n, 0);
      bfr[n][1] = rdB(buf, nh, n, 1);
    }
  };

  const int NT = K >> 6, NI = K >> 7;

  stage_unit(Ab, 0, 0, 0);            // Ah0(t0)
  stage_unit(Ab, 16384, 128, 0);      // Ah1(t0)
  stage_unit(Bb, 65536, 0, 0);        // B(t0)
  stage_unit(Ab, 32768, 0, 1);        // Ah0(t1)
  asm volatile("s_waitcnt vmcnt(2)" ::: "memory");
  GBAR();

  for (int i = 0; i < NI; ++i) {
    const int tb = (2 * i + 1) & (NT - 1);
    const int tc = (2 * i + 2) & (NT - 1);
    const int td = (2 * i + 3) & (NT - 1);
    readA(0); readB(0, 0);
    stage_unit(Ab, 32768 + 16384, 128, tb);
    stage_unit(Bb, 65536 + 16384, 0, tb);
    PWAIT();
    mq<0>(acc, afr, bfr); GBAR();
    readB(0, 1);
    stage_unit(Ab, 0, 0, tc);
    stage_unit(Ab, 16384, 128, tc);
    PWAITV4();
    mq<1>(acc, afr, bfr); GBAR();
    readA(1); readB(1, 0);
    stage_unit(Bb, 65536, 0, tc);
    PWAIT();
    mq<0>(acc, afr, bfr); GBAR();
    readB(1, 1);
    stage_unit(Ab, 32768, 0, td);
    PWAITV();
    mq<1>(acc, afr, bfr); GBAR();
  }

  const int crow = bm * 256 + wr * 64;
  const int ccol = bn * 128 + wc * 64;
#pragma unroll
  for (int mf = 0; mf < 4; ++mf)
#pragma unroll
    for (int nf = 0; nf < 4; ++nf)
#pragma unroll
      for (int r = 0; r < 4; ++r) {
        int row = crow + mf * 16 + laneG * 4 + r;
        int col = ccol + nf * 16 + laneR;
        float v = acc[mf][nf][r];
        if constexpr (sizeof(OutT) == 2)
          C[(size_t)row * N + col] = f2bf(v);
        else
          C[(size_t)row * N + col] = v;
      }
}

// ---------------- flash attention (R18 exact: R14 body, no setprio) ----------
__global__ __launch_bounds__(512, 4) void flash_attn(
    const u16* __restrict__ QKV, u16* __restrict__ O) {
  constexpr int S = 2048, DQ = 3072, DO = 1024;
  __shared__ u16 Kt[3][4096];
  __shared__ u16 Vt[3][4096];
  const int tid = threadIdx.x, wid = tid >> 6, lane = tid & 63;
  const int lq = lane & 31, hi = lane >> 5;

  const int id = blockIdx.x;
  const int jj0 = id >> 3;
  const int bh = (id & 7) * 8 + (jj0 >> 3), qt = jj0 & 7;
  const int b = bh >> 4, h = bh & 15;

  const size_t bq = (size_t)b * S * DQ;
  const u16* Qg = QKV + bq + h * 64;
  const u16* Kg = QKV + bq + 1024 + h * 64;
  const u16* Vg = QKV + bq + 2048 + h * 64;
  const int qrow0 = qt * 256 + wid * 32;

  const int k_kv = tid >> 3;
  const int k_col = ((tid & 7) ^ (k_kv & 7)) * 8;
  const int v_kv = ((tid >> 5) << 2) | ((tid >> 1) & 3);
  const int v_hd = (((tid >> 3) & 3) << 4) | ((tid & 1) << 3);

  bf16x8 qf[4];
#pragma unroll
  for (int kc = 0; kc < 4; ++kc)
    qf[kc] = *(const bf16x8*)&Qg[(size_t)(qrow0 + lq) * DQ + kc * 16 + hi * 8];

  f32x16 o0, o1;
#pragma unroll
  for (int r = 0; r < 16; ++r) { o0[r] = 0.f; o1[r] = 0.f; }
  float l = 0.f;

  auto stage = [&](int buf, int kv0) {
    load_lds16(Kg + (size_t)(kv0 + k_kv) * DQ + k_col, &Kt[buf][wid * 512]);
    load_lds16(Vg + (size_t)(kv0 + v_kv) * DQ + v_hd, &Vt[buf][wid * 512]);
  };

  stage(0, 0);
  stage(1, 64);
  asm volatile("s_waitcnt vmcnt(2)" ::: "memory");
  __builtin_amdgcn_s_barrier();
  asm volatile("" ::: "memory");

  int cur = 0, pre = 2;
  for (int t = 0; t < 32; ++t) {
    stage(pre, ((t + 2) & 31) * 64);

    f32x16 st[2];
#pragma unroll
    for (int blk = 0; blk < 2; ++blk) {
#pragma unroll
      for (int r = 0; r < 16; ++r) st[blk][r] = 0.f;
      bf16x8 kf[4];
#pragma unroll
      for (int kc = 0; kc < 4; ++kc) {
        int kv = blk * 32 + lq;
        int byt = kv * 128 + ((kc * 32 + hi * 16) ^ ((kv & 7) << 4));
        kf[kc] = *(const bf16x8*)((const char*)&Kt[cur][0] + byt);
      }
#pragma unroll
      for (int kc = 0; kc < 4; ++kc)
        st[blk] = __builtin_amdgcn_mfma_f32_32x32x16_bf16(kf[kc], qf[kc], st[blk], 0, 0, 0);
    }

    float ps = 0.f;
#pragma unroll
    for (int blk = 0; blk < 2; ++blk)
#pragma unroll
      for (int r = 0; r < 16; ++r) {
        float p = exp2_fast(st[blk][r]);
        st[blk][r] = p;
        ps += p;
      }
    l += ps;

    u32 W0[8], W1[8];
#pragma unroll
    for (int r2 = 0; r2 < 8; ++r2) {
      W0[r2] = cvt_pk_bf16(st[0][2 * r2], st[0][2 * r2 + 1]);
      W1[r2] = cvt_pk_bf16(st[1][2 * r2], st[1][2 * r2 + 1]);
    }
    bf16x8 pb[4];
#pragma unroll
    for (int ks = 0; ks < 2; ++ks) {
      u32 a0 = W0[4 * ks], a2 = W0[4 * ks + 2];
      u32 a1 = W0[4 * ks + 1], a3 = W0[4 * ks + 3];
      permlane32_swap(a0, a2);
      permlane32_swap(a1, a3);
      pb[ks] = __builtin_bit_cast(bf16x8, u32x4{a0, a1, a2, a3});
    }
#pragma unroll
    for (int ks = 0; ks < 2; ++ks) {
      u32 a0 = W1[4 * ks], a2 = W1[4 * ks + 2];
      u32 a1 = W1[4 * ks + 1], a3 = W1[4 * ks + 3];
      permlane32_swap(a0, a2);
      permlane32_swap(a1, a3);
      pb[2 + ks] = __builtin_bit_cast(bf16x8, u32x4{a0, a1, a2, a3});
    }

#pragma unroll
    for (int c2 = 0; c2 < 2; ++c2) {
      bf16x4 vh[4][2];
      const int hb = c2 * 2 + ((lane >> 4) & 1);
#pragma unroll
      for (int ks = 0; ks < 4; ++ks)
#pragma unroll
        for (int p2 = 0; p2 < 2; ++p2) {
          int a = ks * 4 + hi * 2 + p2;
          vh[ks][p2] = tr16(&Vt[cur][(a * 4 + hb) * 64 + (lane & 15) * 4]);
        }
      asm volatile("s_waitcnt lgkmcnt(0)" ::: "memory");
      __builtin_amdgcn_sched_barrier(0);
      f32x16 oc = c2 ? o1 : o0;
#pragma unroll
      for (int ks = 0; ks < 4; ++ks) {
        bf16x8 vf = __builtin_shufflevector(vh[ks][0], vh[ks][1], 0, 1, 2, 3, 4, 5, 6, 7);
        oc = __builtin_amdgcn_mfma_f32_32x32x16_bf16(vf, pb[ks], oc, 0, 0, 0);
      }
      if (c2) o1 = oc; else o0 = oc;
    }

    asm volatile("s_waitcnt vmcnt(2)" ::: "memory");
    __builtin_amdgcn_s_barrier();
    asm volatile("" ::: "memory");

    cur = (cur == 2) ? 0 : cur + 1;
    pre = (pre == 2) ? 0 : pre + 1;
  }

  l += __shfl_xor(l, 32);
  const float inv = 1.0f / l;
  const size_t boo = (size_t)b * S * DO + h * 64;
  const size_t qb = boo + (size_t)(qrow0 + lq) * DO;
#pragma unroll
  for (int r = 0; r < 16; ++r) {
    int hd = (r & 3) + 8 * (r >> 2) + 4 * hi;
    O[qb + hd] = f2bf(o0[r] * inv);
    O[qb + 32 + hd] = f2bf(o1[r] * inv);
  }
}

extern "C" void kernel_launch(void* const* d_in, const int* in_sizes, int n_in,
                              void* d_out, int out_size, void* d_ws, size_t ws_size,
                              hipStream_t stream) {
  const float* hs = (const float*)d_in[0];
  const float* Wq = (const float*)d_in[1];
  const float* Wk = (const float*)d_in[2];
  const float* Wv = (const float*)d_in[3];
  const float* Wo = (const float*)d_in[4];
  float* out = (float*)d_out;

  constexpr int Bn = 4, S = 2048, Dm = 1024;
  constexpr int M = Bn * S;                  // 8192
  constexpr size_t SZ = (size_t)M * Dm;
  constexpr size_t WSZ = (size_t)Dm * Dm;

  u16* wsp = (u16*)d_ws;
  u16* QKVb = wsp;                      // [M][3072] bf16 = 48 MB
  u16* hs16 = QKVb + (size_t)M * 3072;  // 16 MB
  u16* Ob = hs16;                       // alias: hs16 dead after QKV GEMM
  u16* W16 = hs16 + SZ;                 // Wq|Wk|Wv|Wo concat (contiguous)
  u16* Wo16 = W16 + 3 * WSZ;
  (void)ws_size; (void)in_sizes; (void)n_in; (void)out_size;

  // fused conversion: hs + 4 weights in one launch.
  // 1/sqrt(64) * log2(e) folded into Wq (softmax runs in base-2 domain).
  constexpr int HS4 = (int)(SZ / 4);
  constexpr int W4SEG = (int)(WSZ / 4);
  cvt_all<<<(HS4 + 4 * W4SEG) / 256, 256, 0, stream>>>(
      hs, Wq, Wk, Wv, Wo, hs16, W16, HS4, W4SEG, 0.125f * 1.44269504f);

  // fused QKV projection: 4-phase 256x128, grid 768 = exactly 3 rounds,
  // supertiled chunks 8bm x 12bn.
  gemm256x128<u16><<<(M / 256) * (3072 / 128), 512, 0, stream>>>(
      hs16, W16, QKVb, M, 3072, Dm, 8, 12);

  flash_attn<<<512, 512, 0, stream>>>(QKVb, Ob);

  // output projection: 4-phase 256x128, grid 256 = exactly 1 round,
  // supertiled chunks 4bm x 8bn (R20-proven).
  gemm256x128<float><<<(M / 256) * (Dm / 128), 512, 0, stream>>>(
      Ob, Wo16, out, M, Dm, Dm, 4, 8);
}